// Round 2
// baseline (5105.316 us; speedup 1.0000x reference)
//
#include <hip/hip_runtime.h>
#include <math.h>

// ---------------- constants ----------------
#define D_MODEL 768
#define N_HEADS 12
#define D_HEAD  64
#define D_MLP   3072
#define BATCH   2
#define SEQ     2048
#define ROWS    (BATCH * SEQ)          // 4096
#define LN_EPS  1e-5f

// ---------------- LayerNorm ----------------
// one block (256 thr) per row of 768
__global__ __launch_bounds__(256) void ln_kernel(const float* __restrict__ x,
                                                 const float* __restrict__ w,
                                                 const float* __restrict__ b,
                                                 float* __restrict__ y) {
    int row = blockIdx.x;
    const float* xr = x + (size_t)row * D_MODEL;
    float v[3];
    float s = 0.f, sq = 0.f;
#pragma unroll
    for (int u = 0; u < 3; ++u) {
        v[u] = xr[threadIdx.x + u * 256];
        s += v[u];
        sq += v[u] * v[u];
    }
#pragma unroll
    for (int off = 32; off >= 1; off >>= 1) {
        s  += __shfl_xor(s, off);
        sq += __shfl_xor(sq, off);
    }
    __shared__ float ss[4], ssq[4];
    int wave = threadIdx.x >> 6;
    int lane = threadIdx.x & 63;
    if (lane == 0) { ss[wave] = s; ssq[wave] = sq; }
    __syncthreads();
    s = ss[0] + ss[1] + ss[2] + ss[3];
    sq = ssq[0] + ssq[1] + ssq[2] + ssq[3];
    float mean = s * (1.0f / D_MODEL);
    float var = sq * (1.0f / D_MODEL) - mean * mean;
    float rstd = rsqrtf(var + LN_EPS);
    float* yr = y + (size_t)row * D_MODEL;
#pragma unroll
    for (int u = 0; u < 3; ++u) {
        int idx = threadIdx.x + u * 256;
        yr[idx] = (v[u] - mean) * rstd * w[idx] + b[idx];
    }
}

// ---------------- GELU (GPT-2 'new') ----------------
__device__ __forceinline__ float gelu_new_f(float x) {
    float x3 = x * x * x;
    float t = tanhf(0.7978845608028654f * (x + 0.044715f * x3));
    return 0.5f * x * (1.0f + t);
}

// ---------------- Generic tiled fp32 GEMM ----------------
// C[M,N] = A[M,K] @ B + bias (+gelu) (+resid)
// B addressing: element B[k][n] = B_ptr + (n/64)*nblock_stride + k*ldb + (n%64)
//   standard row-major [K,N]:  nblock_stride=64,     ldb=N
//   W_Q/K/V [head][e][h]:      nblock_stride=768*64, ldb=64
#define BM 64
#define BN 64
#define BK 16

__global__ __launch_bounds__(256) void gemm_kernel(
        const float* __restrict__ A, int lda,
        const float* __restrict__ B, int ldb, int nblock_stride,
        const float* __restrict__ bias,
        const float* __restrict__ resid,
        float* __restrict__ C, int ldc,
        int M, int N, int K, int gelu_flag) {
    __shared__ float As[BK][BM + 4];   // stored transposed: As[k][m]
    __shared__ float Bs[BK][BN + 4];

    int tx = threadIdx.x;
    int m0 = blockIdx.y * BM;
    int n0 = blockIdx.x * BN;
    const float* Bblk = B + (size_t)(n0 >> 6) * nblock_stride;

    float acc[4][4] = {};

    int r = tx >> 4;          // 0..15 (row group)
    int c = tx & 15;          // 0..15 (col group)
    int a_m = tx >> 2;        // 0..63
    int a_k = (tx & 3) * 4;   // 0,4,8,12
    int b_k = tx >> 4;        // 0..15
    int b_j = (tx & 15) * 4;  // 0..60

    for (int k0 = 0; k0 < K; k0 += BK) {
        float4 av = *reinterpret_cast<const float4*>(A + (size_t)(m0 + a_m) * lda + k0 + a_k);
        float4 bv = *reinterpret_cast<const float4*>(Bblk + (size_t)(k0 + b_k) * ldb + b_j);
        As[a_k + 0][a_m] = av.x;
        As[a_k + 1][a_m] = av.y;
        As[a_k + 2][a_m] = av.z;
        As[a_k + 3][a_m] = av.w;
        *reinterpret_cast<float4*>(&Bs[b_k][b_j]) = bv;
        __syncthreads();
#pragma unroll
        for (int kk = 0; kk < BK; ++kk) {
            float a0 = As[kk][r * 4 + 0];
            float a1 = As[kk][r * 4 + 1];
            float a2 = As[kk][r * 4 + 2];
            float a3 = As[kk][r * 4 + 3];
            float b0 = Bs[kk][c * 4 + 0];
            float b1 = Bs[kk][c * 4 + 1];
            float b2 = Bs[kk][c * 4 + 2];
            float b3 = Bs[kk][c * 4 + 3];
            acc[0][0] = fmaf(a0, b0, acc[0][0]); acc[0][1] = fmaf(a0, b1, acc[0][1]);
            acc[0][2] = fmaf(a0, b2, acc[0][2]); acc[0][3] = fmaf(a0, b3, acc[0][3]);
            acc[1][0] = fmaf(a1, b0, acc[1][0]); acc[1][1] = fmaf(a1, b1, acc[1][1]);
            acc[1][2] = fmaf(a1, b2, acc[1][2]); acc[1][3] = fmaf(a1, b3, acc[1][3]);
            acc[2][0] = fmaf(a2, b0, acc[2][0]); acc[2][1] = fmaf(a2, b1, acc[2][1]);
            acc[2][2] = fmaf(a2, b2, acc[2][2]); acc[2][3] = fmaf(a2, b3, acc[2][3]);
            acc[3][0] = fmaf(a3, b0, acc[3][0]); acc[3][1] = fmaf(a3, b1, acc[3][1]);
            acc[3][2] = fmaf(a3, b2, acc[3][2]); acc[3][3] = fmaf(a3, b3, acc[3][3]);
        }
        __syncthreads();
    }

#pragma unroll
    for (int i = 0; i < 4; ++i) {
#pragma unroll
        for (int j = 0; j < 4; ++j) {
            int m = m0 + r * 4 + i;
            int n = n0 + c * 4 + j;
            float val = acc[i][j];
            if (bias) val += bias[n];
            if (gelu_flag) val = gelu_new_f(val);
            if (resid) val += resid[(size_t)m * ldc + n];
            C[(size_t)m * ldc + n] = val;
        }
    }
}

// ---------------- causal attention (flash-style, one wave per q row) ----------------
// q,k,v,z layout: [B*S, N_HEADS*D_HEAD] row-major ([b,s,head,d])
// z may ALIAS q: each wave reads its q element once before writing z at the
// same address, and no other wave touches that element.
__global__ __launch_bounds__(256) void attn_kernel(const float* __restrict__ q,
                                                   const float* __restrict__ k,
                                                   const float* __restrict__ v,
                                                   float* __restrict__ z) {
    int wave = threadIdx.x >> 6;
    int lane = threadIdx.x & 63;
    int qrow = blockIdx.x * 4 + wave;
    int head = blockIdx.y;
    int batch = blockIdx.z;

    size_t base = ((size_t)batch * SEQ) * (N_HEADS * D_HEAD) + head * D_HEAD;
    const float* qptr = q + base + (size_t)qrow * (N_HEADS * D_HEAD);
    float qd = qptr[lane] * 0.125f;   // 1/sqrt(64)

    float m = -3.0e38f;
    float l = 0.f;
    float acc = 0.f;

    for (int kk = 0; kk <= qrow; ++kk) {
        const float* kptr = k + base + (size_t)kk * (N_HEADS * D_HEAD);
        const float* vptr = v + base + (size_t)kk * (N_HEADS * D_HEAD);
        float s = qd * kptr[lane];
#pragma unroll
        for (int off = 32; off >= 1; off >>= 1) s += __shfl_xor(s, off);
        float mnew = fmaxf(m, s);
        float corr = __expf(m - mnew);
        float p = __expf(s - mnew);
        l = l * corr + p;
        acc = acc * corr + p * vptr[lane];
        m = mnew;
    }
    z[base + (size_t)qrow * (N_HEADS * D_HEAD) + lane] = acc / l;
}

// ---------------- launch ----------------
// Workspace budget: only 3R floats (37.7 MB). d_out doubles as scratch for
// x_ln1 then resid_mid (each element fully rewritten before use/validation).
extern "C" void kernel_launch(void* const* d_in, const int* in_sizes, int n_in,
                              void* d_out, int out_size, void* d_ws, size_t ws_size,
                              hipStream_t stream) {
    const float* resid_pre = (const float*)d_in[0];
    const float* W_Q  = (const float*)d_in[1];
    const float* b_Q  = (const float*)d_in[2];
    const float* W_K  = (const float*)d_in[3];
    const float* b_K  = (const float*)d_in[4];
    const float* W_V  = (const float*)d_in[5];
    const float* b_V  = (const float*)d_in[6];
    const float* W_O  = (const float*)d_in[7];
    const float* b_O  = (const float*)d_in[8];
    const float* ln1_w = (const float*)d_in[9];
    const float* ln1_b = (const float*)d_in[10];
    const float* ln2_w = (const float*)d_in[11];
    const float* ln2_b = (const float*)d_in[12];
    const float* W_in  = (const float*)d_in[13];
    const float* b_in  = (const float*)d_in[14];
    const float* W_out = (const float*)d_in[15];
    const float* b_out = (const float*)d_in[16];
    float* out = (float*)d_out;

    const size_t R = (size_t)ROWS * D_MODEL;   // 4096*768 = 3,145,728 floats
    float* ws = (float*)d_ws;
    float* qbuf = ws;                // [0,R)   q, then z (aliased), then x_ln2... no:
    float* kbuf = ws + R;            // [R,2R)  k, then x_ln2
    float* vbuf = ws + 2 * R;        // [2R,3R) v, then MLP hidden chunk
    float* zbuf = qbuf;              // alias (safe, see attn_kernel comment)
    float* x_ln1 = out;              // d_out as scratch
    float* x_ln2 = kbuf;             // k dead after attention
    float* hidden = vbuf;            // v dead after attention; 1024*3072 = R floats
    float* resid_mid = out;          // d_out again (x_ln1 dead after QKV)

    dim3 blk(256);
    dim3 g768(D_MODEL / BN, ROWS / BM);    // (12, 64)

    // 1. ln1 -> d_out
    ln_kernel<<<ROWS, blk, 0, stream>>>(resid_pre, ln1_w, ln1_b, x_ln1);
    // 2-4. Q,K,V projections  (B layout: [head][e][h] -> nblock_stride=768*64, ldb=64)
    gemm_kernel<<<g768, blk, 0, stream>>>(x_ln1, D_MODEL, W_Q, 64, D_MODEL * 64, b_Q, nullptr,
                                          qbuf, D_MODEL, ROWS, D_MODEL, D_MODEL, 0);
    gemm_kernel<<<g768, blk, 0, stream>>>(x_ln1, D_MODEL, W_K, 64, D_MODEL * 64, b_K, nullptr,
                                          kbuf, D_MODEL, ROWS, D_MODEL, D_MODEL, 0);
    gemm_kernel<<<g768, blk, 0, stream>>>(x_ln1, D_MODEL, W_V, 64, D_MODEL * 64, b_V, nullptr,
                                          vbuf, D_MODEL, ROWS, D_MODEL, D_MODEL, 0);
    // 5. attention (z aliases q)
    attn_kernel<<<dim3(SEQ / 4, N_HEADS, BATCH), blk, 0, stream>>>(qbuf, kbuf, vbuf, zbuf);
    // 6. output projection + residual -> d_out  (W_O flattens to row-major [768,768])
    gemm_kernel<<<g768, blk, 0, stream>>>(zbuf, D_MODEL, W_O, D_MODEL, 64, b_O, resid_pre,
                                          resid_mid, D_MODEL, ROWS, D_MODEL, D_MODEL, 0);
    // 7. ln2: d_out -> x_ln2 (k's slot)
    ln_kernel<<<ROWS, blk, 0, stream>>>(resid_mid, ln2_w, ln2_b, x_ln2);
    // 8-9. MLP in 4 row-chunks of 1024 (hidden chunk fits in R floats at v's slot)
    const int CH = 1024;
    dim3 g_in(D_MLP / BN, CH / BM);    // (48, 16)
    dim3 g_out(D_MODEL / BN, CH / BM); // (12, 16)
    for (int c = 0; c < ROWS / CH; ++c) {
        const float* xc = x_ln2 + (size_t)c * CH * D_MODEL;
        float* oc = out + (size_t)c * CH * D_MODEL;
        // hidden = gelu(xc @ W_in + b_in)
        gemm_kernel<<<g_in, blk, 0, stream>>>(xc, D_MODEL, W_in, D_MLP, 64, b_in, nullptr,
                                              hidden, D_MLP, CH, D_MLP, D_MODEL, 1);
        // out_chunk = hidden @ W_out + b_out + resid_mid_chunk (in-place on d_out)
        gemm_kernel<<<g_out, blk, 0, stream>>>(hidden, D_MLP, W_out, D_MODEL, 64, b_out, oc,
                                               oc, D_MODEL, CH, D_MODEL, D_MLP, 0);
    }
}

// Round 3
// 2171.072 us; speedup vs baseline: 2.3515x; 2.3515x over previous
//
#include <hip/hip_runtime.h>
#include <math.h>

// ---------------- constants ----------------
#define D_MODEL 768
#define N_HEADS 12
#define D_HEAD  64
#define D_MLP   3072
#define BATCH   2
#define SEQ     2048
#define ROWS    (BATCH * SEQ)          // 4096
#define LN_EPS  1e-5f

// ---------------- LayerNorm ----------------
__global__ __launch_bounds__(256) void ln_kernel(const float* __restrict__ x,
                                                 const float* __restrict__ w,
                                                 const float* __restrict__ b,
                                                 float* __restrict__ y) {
    int row = blockIdx.x;
    const float* xr = x + (size_t)row * D_MODEL;
    float v[3];
    float s = 0.f, sq = 0.f;
#pragma unroll
    for (int u = 0; u < 3; ++u) {
        v[u] = xr[threadIdx.x + u * 256];
        s += v[u];
        sq += v[u] * v[u];
    }
#pragma unroll
    for (int off = 32; off >= 1; off >>= 1) {
        s  += __shfl_xor(s, off);
        sq += __shfl_xor(sq, off);
    }
    __shared__ float ss[4], ssq[4];
    int wave = threadIdx.x >> 6;
    int lane = threadIdx.x & 63;
    if (lane == 0) { ss[wave] = s; ssq[wave] = sq; }
    __syncthreads();
    s = ss[0] + ss[1] + ss[2] + ss[3];
    sq = ssq[0] + ssq[1] + ssq[2] + ssq[3];
    float mean = s * (1.0f / D_MODEL);
    float var = sq * (1.0f / D_MODEL) - mean * mean;
    float rstd = rsqrtf(var + LN_EPS);
    float* yr = y + (size_t)row * D_MODEL;
#pragma unroll
    for (int u = 0; u < 3; ++u) {
        int idx = threadIdx.x + u * 256;
        yr[idx] = (v[u] - mean) * rstd * w[idx] + b[idx];
    }
}

// ---------------- GELU (GPT-2 'new') ----------------
__device__ __forceinline__ float gelu_new_f(float x) {
    float x3 = x * x * x;
    float t = tanhf(0.7978845608028654f * (x + 0.044715f * x3));
    return 0.5f * x * (1.0f + t);
}

// ---------------- Generic tiled fp32 GEMM ----------------
#define BM 64
#define BN 64
#define BK 16

__global__ __launch_bounds__(256) void gemm_kernel(
        const float* __restrict__ A, int lda,
        const float* __restrict__ B, int ldb, int nblock_stride,
        const float* __restrict__ bias,
        const float* __restrict__ resid,
        float* __restrict__ C, int ldc,
        int M, int N, int K, int gelu_flag) {
    __shared__ float As[BK][BM + 4];
    __shared__ float Bs[BK][BN + 4];

    int tx = threadIdx.x;
    int m0 = blockIdx.y * BM;
    int n0 = blockIdx.x * BN;
    const float* Bblk = B + (size_t)(n0 >> 6) * nblock_stride;

    float acc[4][4] = {};

    int r = tx >> 4;
    int c = tx & 15;
    int a_m = tx >> 2;
    int a_k = (tx & 3) * 4;
    int b_k = tx >> 4;
    int b_j = (tx & 15) * 4;

    for (int k0 = 0; k0 < K; k0 += BK) {
        float4 av = *reinterpret_cast<const float4*>(A + (size_t)(m0 + a_m) * lda + k0 + a_k);
        float4 bv = *reinterpret_cast<const float4*>(Bblk + (size_t)(k0 + b_k) * ldb + b_j);
        As[a_k + 0][a_m] = av.x;
        As[a_k + 1][a_m] = av.y;
        As[a_k + 2][a_m] = av.z;
        As[a_k + 3][a_m] = av.w;
        *reinterpret_cast<float4*>(&Bs[b_k][b_j]) = bv;
        __syncthreads();
#pragma unroll
        for (int kk = 0; kk < BK; ++kk) {
            float a0 = As[kk][r * 4 + 0];
            float a1 = As[kk][r * 4 + 1];
            float a2 = As[kk][r * 4 + 2];
            float a3 = As[kk][r * 4 + 3];
            float b0 = Bs[kk][c * 4 + 0];
            float b1 = Bs[kk][c * 4 + 1];
            float b2 = Bs[kk][c * 4 + 2];
            float b3 = Bs[kk][c * 4 + 3];
            acc[0][0] = fmaf(a0, b0, acc[0][0]); acc[0][1] = fmaf(a0, b1, acc[0][1]);
            acc[0][2] = fmaf(a0, b2, acc[0][2]); acc[0][3] = fmaf(a0, b3, acc[0][3]);
            acc[1][0] = fmaf(a1, b0, acc[1][0]); acc[1][1] = fmaf(a1, b1, acc[1][1]);
            acc[1][2] = fmaf(a1, b2, acc[1][2]); acc[1][3] = fmaf(a1, b3, acc[1][3]);
            acc[2][0] = fmaf(a2, b0, acc[2][0]); acc[2][1] = fmaf(a2, b1, acc[2][1]);
            acc[2][2] = fmaf(a2, b2, acc[2][2]); acc[2][3] = fmaf(a2, b3, acc[2][3]);
            acc[3][0] = fmaf(a3, b0, acc[3][0]); acc[3][1] = fmaf(a3, b1, acc[3][1]);
            acc[3][2] = fmaf(a3, b2, acc[3][2]); acc[3][3] = fmaf(a3, b3, acc[3][3]);
        }
        __syncthreads();
    }

#pragma unroll
    for (int i = 0; i < 4; ++i) {
#pragma unroll
        for (int j = 0; j < 4; ++j) {
            int m = m0 + r * 4 + i;
            int n = n0 + c * 4 + j;
            float val = acc[i][j];
            if (bias) val += bias[n];
            if (gelu_flag) val = gelu_new_f(val);
            if (resid) val += resid[(size_t)m * ldc + n];
            C[(size_t)m * ldc + n] = val;
        }
    }
}

// ---------------- wave reductions ----------------
__device__ __forceinline__ float wred_max(float x) {
#pragma unroll
    for (int o = 32; o >= 1; o >>= 1) x = fmaxf(x, __shfl_xor(x, o));
    return x;
}
__device__ __forceinline__ float wred_sum(float x) {
#pragma unroll
    for (int o = 32; o >= 1; o >>= 1) x += __shfl_xor(x, o);
    return x;
}

// ---------------- causal flash attention, tile-parallel ----------------
// 16 q rows per block (4 waves x 4 rows/wave); K/V staged in LDS 64-key tiles.
// QK: lane j <-> key j (64 keys in parallel). PV: lane d <-> output dim d.
// z may alias q: each block reads only its own 16 q rows (at start) and
// writes z to those same rows (at end); K/V are separate buffers.
__global__ __launch_bounds__(256) void attn_kernel(const float* __restrict__ q,
                                                   const float* __restrict__ k,
                                                   const float* __restrict__ v,
                                                   float* __restrict__ z) {
    __shared__ float Ks[64][66];
    __shared__ float Vs[64][66];
    __shared__ float Qs[16][64];
    __shared__ float Ps[4][4][64];

    int tid = threadIdx.x;
    int wave = tid >> 6, lane = tid & 63;
    int head = blockIdx.y, batch = blockIdx.z;
    int qbase = blockIdx.x * 16;
    const int rs = N_HEADS * D_HEAD;  // 768
    size_t hbase = ((size_t)batch * SEQ) * rs + (size_t)head * D_HEAD;

    // stage my block's 16 q rows (pre-scaled by 1/sqrt(64))
    {
        int row = tid >> 4;
        int c4 = (tid & 15) << 2;
        float4 qv = *reinterpret_cast<const float4*>(q + hbase + (size_t)(qbase + row) * rs + c4);
        Qs[row][c4 + 0] = qv.x * 0.125f;
        Qs[row][c4 + 1] = qv.y * 0.125f;
        Qs[row][c4 + 2] = qv.z * 0.125f;
        Qs[row][c4 + 3] = qv.w * 0.125f;
    }

    int w4 = wave * 4;
    int qr = qbase + w4;             // first of my 4 q rows
    float m0 = -1e30f, m1 = -1e30f, m2 = -1e30f, m3 = -1e30f;
    float l0 = 0, l1 = 0, l2 = 0, l3 = 0;
    float o0 = 0, o1 = 0, o2 = 0, o3 = 0;

    for (int kt = 0; kt < qbase + 16; kt += 64) {
        __syncthreads();   // previous tile fully consumed (and Qs staged, iter 0)
#pragma unroll
        for (int i = 0; i < 4; ++i) {
            int idx = tid + (i << 8);
            int row = idx >> 4;
            int c4 = (idx & 15) << 2;
            size_t g = hbase + (size_t)(kt + row) * rs + c4;
            float4 kv = *reinterpret_cast<const float4*>(k + g);
            float4 vv = *reinterpret_cast<const float4*>(v + g);
            Ks[row][c4 + 0] = kv.x; Ks[row][c4 + 1] = kv.y;
            Ks[row][c4 + 2] = kv.z; Ks[row][c4 + 3] = kv.w;
            Vs[row][c4 + 0] = vv.x; Vs[row][c4 + 1] = vv.y;
            Vs[row][c4 + 2] = vv.z; Vs[row][c4 + 3] = vv.w;
        }
        __syncthreads();

        // QK^T: lane j computes scores for key kt+j against my 4 rows
        float s0 = 0, s1 = 0, s2 = 0, s3 = 0;
#pragma unroll
        for (int d = 0; d < 64; d += 2) {
            float2 kk = *reinterpret_cast<const float2*>(&Ks[lane][d]);
            float2 qa = *reinterpret_cast<const float2*>(&Qs[w4 + 0][d]);
            float2 qb = *reinterpret_cast<const float2*>(&Qs[w4 + 1][d]);
            float2 qc = *reinterpret_cast<const float2*>(&Qs[w4 + 2][d]);
            float2 qd = *reinterpret_cast<const float2*>(&Qs[w4 + 3][d]);
            s0 = fmaf(qa.x, kk.x, s0); s0 = fmaf(qa.y, kk.y, s0);
            s1 = fmaf(qb.x, kk.x, s1); s1 = fmaf(qb.y, kk.y, s1);
            s2 = fmaf(qc.x, kk.x, s2); s2 = fmaf(qc.y, kk.y, s2);
            s3 = fmaf(qd.x, kk.x, s3); s3 = fmaf(qd.y, kk.y, s3);
        }

        int key = kt + lane;
        // online softmax update per row; write p to LDS for PV broadcast
        {
            float sm = (key <= qr + 0) ? s0 : -1e30f;
            float mn = fmaxf(m0, wred_max(sm));
            float corr = __expf(m0 - mn);
            float p = __expf(sm - mn);
            l0 = l0 * corr + wred_sum(p);
            o0 *= corr; m0 = mn;
            Ps[wave][0][lane] = p;
        }
        {
            float sm = (key <= qr + 1) ? s1 : -1e30f;
            float mn = fmaxf(m1, wred_max(sm));
            float corr = __expf(m1 - mn);
            float p = __expf(sm - mn);
            l1 = l1 * corr + wred_sum(p);
            o1 *= corr; m1 = mn;
            Ps[wave][1][lane] = p;
        }
        {
            float sm = (key <= qr + 2) ? s2 : -1e30f;
            float mn = fmaxf(m2, wred_max(sm));
            float corr = __expf(m2 - mn);
            float p = __expf(sm - mn);
            l2 = l2 * corr + wred_sum(p);
            o2 *= corr; m2 = mn;
            Ps[wave][2][lane] = p;
        }
        {
            float sm = (key <= qr + 3) ? s3 : -1e30f;
            float mn = fmaxf(m3, wred_max(sm));
            float corr = __expf(m3 - mn);
            float p = __expf(sm - mn);
            l3 = l3 * corr + wred_sum(p);
            o3 *= corr; m3 = mn;
            Ps[wave][3][lane] = p;
        }

        // PV: lane d accumulates O[row][d] += sum_j p[row][j] * V[j][d]
#pragma unroll
        for (int j = 0; j < 64; j += 2) {
            float va = Vs[j][lane];
            float vb = Vs[j + 1][lane];
            float2 p0 = *reinterpret_cast<const float2*>(&Ps[wave][0][j]);
            float2 p1 = *reinterpret_cast<const float2*>(&Ps[wave][1][j]);
            float2 p2 = *reinterpret_cast<const float2*>(&Ps[wave][2][j]);
            float2 p3 = *reinterpret_cast<const float2*>(&Ps[wave][3][j]);
            o0 = fmaf(p0.x, va, o0); o0 = fmaf(p0.y, vb, o0);
            o1 = fmaf(p1.x, va, o1); o1 = fmaf(p1.y, vb, o1);
            o2 = fmaf(p2.x, va, o2); o2 = fmaf(p2.y, vb, o2);
            o3 = fmaf(p3.x, va, o3); o3 = fmaf(p3.y, vb, o3);
        }
    }

    z[hbase + (size_t)(qr + 0) * rs + lane] = o0 / l0;
    z[hbase + (size_t)(qr + 1) * rs + lane] = o1 / l1;
    z[hbase + (size_t)(qr + 2) * rs + lane] = o2 / l2;
    z[hbase + (size_t)(qr + 3) * rs + lane] = o3 / l3;
}

// ---------------- launch ----------------
// Workspace budget: 3R floats (37.7 MB). d_out doubles as scratch for
// x_ln1 then resid_mid (each element fully rewritten before use/validation).
extern "C" void kernel_launch(void* const* d_in, const int* in_sizes, int n_in,
                              void* d_out, int out_size, void* d_ws, size_t ws_size,
                              hipStream_t stream) {
    const float* resid_pre = (const float*)d_in[0];
    const float* W_Q  = (const float*)d_in[1];
    const float* b_Q  = (const float*)d_in[2];
    const float* W_K  = (const float*)d_in[3];
    const float* b_K  = (const float*)d_in[4];
    const float* W_V  = (const float*)d_in[5];
    const float* b_V  = (const float*)d_in[6];
    const float* W_O  = (const float*)d_in[7];
    const float* b_O  = (const float*)d_in[8];
    const float* ln1_w = (const float*)d_in[9];
    const float* ln1_b = (const float*)d_in[10];
    const float* ln2_w = (const float*)d_in[11];
    const float* ln2_b = (const float*)d_in[12];
    const float* W_in  = (const float*)d_in[13];
    const float* b_in  = (const float*)d_in[14];
    const float* W_out = (const float*)d_in[15];
    const float* b_out = (const float*)d_in[16];
    float* out = (float*)d_out;

    const size_t R = (size_t)ROWS * D_MODEL;   // 3,145,728 floats
    float* ws = (float*)d_ws;
    float* qbuf = ws;                // [0,R)
    float* kbuf = ws + R;            // [R,2R)
    float* vbuf = ws + 2 * R;        // [2R,3R)
    float* zbuf = qbuf;              // alias (safe, see attn_kernel comment)
    float* x_ln1 = out;              // d_out as scratch
    float* x_ln2 = kbuf;             // k dead after attention
    float* hidden = vbuf;            // v dead after attention
    float* resid_mid = out;          // d_out again

    dim3 blk(256);
    dim3 g768(D_MODEL / BN, ROWS / BM);    // (12, 64)

    // 1. ln1 -> d_out
    ln_kernel<<<ROWS, blk, 0, stream>>>(resid_pre, ln1_w, ln1_b, x_ln1);
    // 2-4. Q,K,V projections  ([head][e][h] -> nblock_stride=768*64, ldb=64)
    gemm_kernel<<<g768, blk, 0, stream>>>(x_ln1, D_MODEL, W_Q, 64, D_MODEL * 64, b_Q, nullptr,
                                          qbuf, D_MODEL, ROWS, D_MODEL, D_MODEL, 0);
    gemm_kernel<<<g768, blk, 0, stream>>>(x_ln1, D_MODEL, W_K, 64, D_MODEL * 64, b_K, nullptr,
                                          kbuf, D_MODEL, ROWS, D_MODEL, D_MODEL, 0);
    gemm_kernel<<<g768, blk, 0, stream>>>(x_ln1, D_MODEL, W_V, 64, D_MODEL * 64, b_V, nullptr,
                                          vbuf, D_MODEL, ROWS, D_MODEL, D_MODEL, 0);
    // 5. attention (z aliases q); 16 q rows per block
    attn_kernel<<<dim3(SEQ / 16, N_HEADS, BATCH), blk, 0, stream>>>(qbuf, kbuf, vbuf, zbuf);
    // 6. output projection + residual -> d_out
    gemm_kernel<<<g768, blk, 0, stream>>>(zbuf, D_MODEL, W_O, D_MODEL, 64, b_O, resid_pre,
                                          resid_mid, D_MODEL, ROWS, D_MODEL, D_MODEL, 0);
    // 7. ln2: d_out -> x_ln2
    ln_kernel<<<ROWS, blk, 0, stream>>>(resid_mid, ln2_w, ln2_b, x_ln2);
    // 8-9. MLP in 4 row-chunks of 1024
    const int CH = 1024;
    dim3 g_in(D_MLP / BN, CH / BM);
    dim3 g_out(D_MODEL / BN, CH / BM);
    for (int c = 0; c < ROWS / CH; ++c) {
        const float* xc = x_ln2 + (size_t)c * CH * D_MODEL;
        float* oc = out + (size_t)c * CH * D_MODEL;
        gemm_kernel<<<g_in, blk, 0, stream>>>(xc, D_MODEL, W_in, D_MLP, 64, b_in, nullptr,
                                              hidden, D_MLP, CH, D_MLP, D_MODEL, 1);
        gemm_kernel<<<g_out, blk, 0, stream>>>(hidden, D_MLP, W_out, D_MODEL, 64, b_out, oc,
                                               oc, D_MODEL, CH, D_MODEL, D_MLP, 0);
    }
}

// Round 4
// 1095.746 us; speedup vs baseline: 4.6592x; 1.9814x over previous
//
#include <hip/hip_runtime.h>
#include <math.h>

typedef unsigned short ushort_t;
typedef __attribute__((ext_vector_type(8))) short bf16x8;
typedef __attribute__((ext_vector_type(4))) float f32x4;

// ---------------- constants ----------------
#define D_MODEL 768
#define N_HEADS 12
#define D_HEAD  64
#define D_MLP   3072
#define BATCH   2
#define SEQ     2048
#define ROWS    (BATCH * SEQ)          // 4096
#define LN_EPS  1e-5f
#define QKV_LD  2304                   // combined q|k|v row stride

// ---------------- bf16 helpers ----------------
__device__ __forceinline__ ushort_t f2bf(float f) {
    unsigned u = __float_as_uint(f);
    u += 0x7fffu + ((u >> 16) & 1u);   // round-to-nearest-even
    return (ushort_t)(u >> 16);
}
__device__ __forceinline__ float bf2f(ushort_t u) {
    return __uint_as_float((unsigned)u << 16);
}

#define GLD16(g, l) __builtin_amdgcn_global_load_lds( \
    (const __attribute__((address_space(1))) void*)(g), \
    (__attribute__((address_space(3))) void*)(l), 16, 0, 0)

// ---------------- LayerNorm (fp32 in -> bf16 out) ----------------
__global__ __launch_bounds__(256) void ln_kernel(const float* __restrict__ x,
                                                 const float* __restrict__ w,
                                                 const float* __restrict__ b,
                                                 ushort_t* __restrict__ y) {
    int row = blockIdx.x;
    const float* xr = x + (size_t)row * D_MODEL;
    float v[3];
    float s = 0.f, sq = 0.f;
#pragma unroll
    for (int u = 0; u < 3; ++u) {
        v[u] = xr[threadIdx.x + u * 256];
        s += v[u];
        sq += v[u] * v[u];
    }
#pragma unroll
    for (int off = 32; off >= 1; off >>= 1) {
        s  += __shfl_xor(s, off);
        sq += __shfl_xor(sq, off);
    }
    __shared__ float ss[4], ssq[4];
    int wave = threadIdx.x >> 6;
    int lane = threadIdx.x & 63;
    if (lane == 0) { ss[wave] = s; ssq[wave] = sq; }
    __syncthreads();
    s = ss[0] + ss[1] + ss[2] + ss[3];
    sq = ssq[0] + ssq[1] + ssq[2] + ssq[3];
    float mean = s * (1.0f / D_MODEL);
    float var = sq * (1.0f / D_MODEL) - mean * mean;
    float rstd = rsqrtf(var + LN_EPS);
    ushort_t* yr = y + (size_t)row * D_MODEL;
#pragma unroll
    for (int u = 0; u < 3; ++u) {
        int idx = threadIdx.x + u * 256;
        yr[idx] = f2bf((v[u] - mean) * rstd * w[idx] + b[idx]);
    }
}

// ---------------- GELU (GPT-2 'new', exp form) ----------------
// 0.5x(1+tanh(y)) = x / (1 + exp(-2y)),  y = sqrt(2/pi)*(x+0.044715x^3)
__device__ __forceinline__ float gelu_new_f(float x) {
    float y2 = -1.5957691216057308f * (x + 0.044715f * x * x * x);
    return x / (1.0f + __expf(y2));
}

// ---------------- tiled transpose + fp32->bf16 convert ----------------
// out[z*out_zs + (c0+c)*out_ld + r0+r] = in[z*in_zs + (r0+r)*in_ld + c0+c]
__global__ __launch_bounds__(256) void transpose_cvt(
        const float* __restrict__ in, int in_ld, long in_zs,
        ushort_t* __restrict__ out, int out_ld, long out_zs) {
    __shared__ float T[64][65];
    long ib = (long)blockIdx.z * in_zs;
    long ob = (long)blockIdx.z * out_zs;
    int r0 = blockIdx.x * 64;
    int c0 = blockIdx.y * 64;
    int tr = threadIdx.x >> 4;          // 0..15
    int tc4 = (threadIdx.x & 15) * 4;   // 0..60
#pragma unroll
    for (int i = 0; i < 4; ++i) {
        int r = i * 16 + tr;
        float4 v = *reinterpret_cast<const float4*>(in + ib + (long)(r0 + r) * in_ld + c0 + tc4);
        T[r][tc4 + 0] = v.x; T[r][tc4 + 1] = v.y;
        T[r][tc4 + 2] = v.z; T[r][tc4 + 3] = v.w;
    }
    __syncthreads();
#pragma unroll
    for (int i = 0; i < 4; ++i) {
        int oc = i * 16 + tr;           // in-col index = out row
        ushort4 o;
        o.x = f2bf(T[tc4 + 0][oc]);
        o.y = f2bf(T[tc4 + 1][oc]);
        o.z = f2bf(T[tc4 + 2][oc]);
        o.w = f2bf(T[tc4 + 3][oc]);
        *reinterpret_cast<ushort4*>(out + ob + (long)(c0 + oc) * out_ld + r0 + tc4) = o;
    }
}

// ---------------- bf16 MFMA GEMM ----------------
// C[M,N] = A[M,K] @ Bt^T   (Bt is [N][K] row-major, ldb = K)
// 128x128 tile, BK=64, 256 threads (4 waves, each 64x64), 16x16x32 MFMA.
// LDS tiles [128 rows][64 k] bf16, XOR-swizzled: byte ^= ((row&7)<<4).
// MODE 0: C bf16 = acc + bias              (QKV)
// MODE 1: C fp32 = acc + bias + resid      (W_O / MLP-out; resid may alias C)
// MODE 2: C bf16 = gelu(acc + bias)        (MLP-in)
template <int MODE>
__global__ __launch_bounds__(256) void mfma_gemm(
        const ushort_t* __restrict__ A, int lda,
        const ushort_t* __restrict__ Bt, int ldb,
        const float* __restrict__ bias,
        const float* __restrict__ resid,
        void* __restrict__ C, int cld, int K) {
    __shared__ char As[16384];
    __shared__ char Bs[16384];
    int tid = threadIdx.x;
    int lane = tid & 63, wv = tid >> 6;
    int wr = wv >> 1, wc = wv & 1;
    int l15 = lane & 15, lhi = lane >> 4;
    int m0 = blockIdx.y * 128, n0 = blockIdx.x * 128;

    f32x4 acc[4][4];
#pragma unroll
    for (int i = 0; i < 4; ++i)
#pragma unroll
        for (int j = 0; j < 4; ++j) acc[i][j] = (f32x4)(0.f);

    // staging geometry (same for A and B tiles): issue i, thread tid covers
    // LDS bytes [(i*256+tid)*16, +16) of the linear tile
    int srow[4], scol[4];
#pragma unroll
    for (int i = 0; i < 4; ++i) {
        int p = (i * 256 + tid) << 4;
        srow[i] = p >> 7;                              // tile row 0..127
        scol[i] = ((p & 127) ^ ((srow[i] & 7) << 4)) >> 1;  // source k-elem (pre-swizzled)
    }
    int lbase = wv << 10;   // wave-uniform LDS byte base within issue block

    for (int k0 = 0; k0 < K; k0 += 64) {
#pragma unroll
        for (int i = 0; i < 4; ++i) {
            const ushort_t* ga = A + (size_t)(m0 + srow[i]) * lda + k0 + scol[i];
            GLD16(ga, As + i * 4096 + lbase);
            const ushort_t* gb = Bt + (size_t)(n0 + srow[i]) * ldb + k0 + scol[i];
            GLD16(gb, Bs + i * 4096 + lbase);
        }
        __syncthreads();

        bf16x8 af[4][2], bfr[4][2];
#pragma unroll
        for (int f = 0; f < 4; ++f)
#pragma unroll
            for (int h = 0; h < 2; ++h) {
                int ar = wr * 64 + f * 16 + l15;
                int ac = h * 64 + lhi * 16;
                af[f][h] = *reinterpret_cast<const bf16x8*>(As + ar * 128 + (ac ^ ((ar & 7) << 4)));
                int br = wc * 64 + f * 16 + l15;
                bfr[f][h] = *reinterpret_cast<const bf16x8*>(Bs + br * 128 + (ac ^ ((br & 7) << 4)));
            }
#pragma unroll
        for (int fm = 0; fm < 4; ++fm)
#pragma unroll
            for (int fn = 0; fn < 4; ++fn) {
                acc[fm][fn] = __builtin_amdgcn_mfma_f32_16x16x32_bf16(af[fm][0], bfr[fn][0], acc[fm][fn], 0, 0, 0);
                acc[fm][fn] = __builtin_amdgcn_mfma_f32_16x16x32_bf16(af[fm][1], bfr[fn][1], acc[fm][fn], 0, 0, 0);
            }
        __syncthreads();
    }

    // epilogue: C/D layout col = lane&15, row = (lane>>4)*4 + i
#pragma unroll
    for (int fm = 0; fm < 4; ++fm)
#pragma unroll
        for (int fn = 0; fn < 4; ++fn)
#pragma unroll
            for (int i = 0; i < 4; ++i) {
                int m = m0 + wr * 64 + fm * 16 + lhi * 4 + i;
                int n = n0 + wc * 64 + fn * 16 + l15;
                float v = acc[fm][fn][i] + bias[n];
                if (MODE == 0) {
                    ((ushort_t*)C)[(size_t)m * cld + n] = f2bf(v);
                } else if (MODE == 1) {
                    ((float*)C)[(size_t)m * cld + n] = v + resid[(size_t)m * cld + n];
                } else {
                    ((ushort_t*)C)[(size_t)m * cld + n] = f2bf(gelu_new_f(v));
                }
            }
}

// ---------------- wave reductions ----------------
__device__ __forceinline__ float wred_max(float x) {
#pragma unroll
    for (int o = 32; o >= 1; o >>= 1) x = fmaxf(x, __shfl_xor(x, o));
    return x;
}
__device__ __forceinline__ float wred_sum(float x) {
#pragma unroll
    for (int o = 32; o >= 1; o >>= 1) x += __shfl_xor(x, o);
    return x;
}

// ---------------- causal flash attention (bf16 io, fp32 math) ----------------
// qkv: [ROWS][2304] bf16 (q|k|v); z: [ROWS][768] bf16
__global__ __launch_bounds__(256) void attn_kernel(const ushort_t* __restrict__ qkv,
                                                   ushort_t* __restrict__ z) {
    __shared__ float Ks[64][66];
    __shared__ float Vs[64][66];
    __shared__ float Qs[16][64];
    __shared__ float Ps[4][4][64];

    int tid = threadIdx.x;
    int wave = tid >> 6, lane = tid & 63;
    int head = blockIdx.y, batch = blockIdx.z;
    int qbase = blockIdx.x * 16;
    size_t rowb = (size_t)batch * SEQ;
    int hcol = head * 64;

    // stage 16 q rows (bf16 -> fp32, pre-scaled)
    {
        int row = tid >> 4;
        int c4 = (tid & 15) << 2;
        const ushort_t* qp = qkv + (rowb + qbase + row) * QKV_LD + hcol + c4;
        ushort4 qv = *reinterpret_cast<const ushort4*>(qp);
        Qs[row][c4 + 0] = bf2f(qv.x) * 0.125f;
        Qs[row][c4 + 1] = bf2f(qv.y) * 0.125f;
        Qs[row][c4 + 2] = bf2f(qv.z) * 0.125f;
        Qs[row][c4 + 3] = bf2f(qv.w) * 0.125f;
    }

    int w4 = wave * 4;
    int qr = qbase + w4;
    float m0 = -1e30f, m1 = -1e30f, m2 = -1e30f, m3 = -1e30f;
    float l0 = 0, l1 = 0, l2 = 0, l3 = 0;
    float o0 = 0, o1 = 0, o2 = 0, o3 = 0;

    for (int kt = 0; kt < qbase + 16; kt += 64) {
        __syncthreads();
#pragma unroll
        for (int it = 0; it < 2; ++it) {
            int idx = it * 256 + tid;
            int row = idx >> 3;
            int c8 = (idx & 7) << 3;
            const ushort_t* kp = qkv + (rowb + kt + row) * QKV_LD + hcol + 768 + c8;
            const ushort_t* vp = qkv + (rowb + kt + row) * QKV_LD + hcol + 1536 + c8;
            uint4 kw = *reinterpret_cast<const uint4*>(kp);
            uint4 vw = *reinterpret_cast<const uint4*>(vp);
            Ks[row][c8 + 0] = bf2f(kw.x & 0xffff); Ks[row][c8 + 1] = bf2f(kw.x >> 16);
            Ks[row][c8 + 2] = bf2f(kw.y & 0xffff); Ks[row][c8 + 3] = bf2f(kw.y >> 16);
            Ks[row][c8 + 4] = bf2f(kw.z & 0xffff); Ks[row][c8 + 5] = bf2f(kw.z >> 16);
            Ks[row][c8 + 6] = bf2f(kw.w & 0xffff); Ks[row][c8 + 7] = bf2f(kw.w >> 16);
            Vs[row][c8 + 0] = bf2f(vw.x & 0xffff); Vs[row][c8 + 1] = bf2f(vw.x >> 16);
            Vs[row][c8 + 2] = bf2f(vw.y & 0xffff); Vs[row][c8 + 3] = bf2f(vw.y >> 16);
            Vs[row][c8 + 4] = bf2f(vw.z & 0xffff); Vs[row][c8 + 5] = bf2f(vw.z >> 16);
            Vs[row][c8 + 6] = bf2f(vw.w & 0xffff); Vs[row][c8 + 7] = bf2f(vw.w >> 16);
        }
        __syncthreads();

        float s0 = 0, s1 = 0, s2 = 0, s3 = 0;
#pragma unroll
        for (int d = 0; d < 64; d += 2) {
            float2 kk = *reinterpret_cast<const float2*>(&Ks[lane][d]);
            float2 qa = *reinterpret_cast<const float2*>(&Qs[w4 + 0][d]);
            float2 qb = *reinterpret_cast<const float2*>(&Qs[w4 + 1][d]);
            float2 qc = *reinterpret_cast<const float2*>(&Qs[w4 + 2][d]);
            float2 qd = *reinterpret_cast<const float2*>(&Qs[w4 + 3][d]);
            s0 = fmaf(qa.x, kk.x, s0); s0 = fmaf(qa.y, kk.y, s0);
            s1 = fmaf(qb.x, kk.x, s1); s1 = fmaf(qb.y, kk.y, s1);
            s2 = fmaf(qc.x, kk.x, s2); s2 = fmaf(qc.y, kk.y, s2);
            s3 = fmaf(qd.x, kk.x, s3); s3 = fmaf(qd.y, kk.y, s3);
        }

        int key = kt + lane;
        {
            float sm = (key <= qr + 0) ? s0 : -1e30f;
            float mn = fmaxf(m0, wred_max(sm));
            float corr = __expf(m0 - mn);
            float p = __expf(sm - mn);
            l0 = l0 * corr + wred_sum(p);
            o0 *= corr; m0 = mn;
            Ps[wave][0][lane] = p;
        }
        {
            float sm = (key <= qr + 1) ? s1 : -1e30f;
            float mn = fmaxf(m1, wred_max(sm));
            float corr = __expf(m1 - mn);
            float p = __expf(sm - mn);
            l1 = l1 * corr + wred_sum(p);
            o1 *= corr; m1 = mn;
            Ps[wave][1][lane] = p;
        }
        {
            float sm = (key <= qr + 2) ? s2 : -1e30f;
            float mn = fmaxf(m2, wred_max(sm));
            float corr = __expf(m2 - mn);
            float p = __expf(sm - mn);
            l2 = l2 * corr + wred_sum(p);
            o2 *= corr; m2 = mn;
            Ps[wave][2][lane] = p;
        }
        {
            float sm = (key <= qr + 3) ? s3 : -1e30f;
            float mn = fmaxf(m3, wred_max(sm));
            float corr = __expf(m3 - mn);
            float p = __expf(sm - mn);
            l3 = l3 * corr + wred_sum(p);
            o3 *= corr; m3 = mn;
            Ps[wave][3][lane] = p;
        }

#pragma unroll
        for (int j = 0; j < 64; j += 2) {
            float va = Vs[j][lane];
            float vb = Vs[j + 1][lane];
            float2 p0 = *reinterpret_cast<const float2*>(&Ps[wave][0][j]);
            float2 p1 = *reinterpret_cast<const float2*>(&Ps[wave][1][j]);
            float2 p2 = *reinterpret_cast<const float2*>(&Ps[wave][2][j]);
            float2 p3 = *reinterpret_cast<const float2*>(&Ps[wave][3][j]);
            o0 = fmaf(p0.x, va, o0); o0 = fmaf(p0.y, vb, o0);
            o1 = fmaf(p1.x, va, o1); o1 = fmaf(p1.y, vb, o1);
            o2 = fmaf(p2.x, va, o2); o2 = fmaf(p2.y, vb, o2);
            o3 = fmaf(p3.x, va, o3); o3 = fmaf(p3.y, vb, o3);
        }
    }

    z[(rowb + qr + 0) * D_MODEL + hcol + lane] = f2bf(o0 / l0);
    z[(rowb + qr + 1) * D_MODEL + hcol + lane] = f2bf(o1 / l1);
    z[(rowb + qr + 2) * D_MODEL + hcol + lane] = f2bf(o2 / l2);
    z[(rowb + qr + 3) * D_MODEL + hcol + lane] = f2bf(o3 / l3);
}

// ---------------- launch ----------------
// ws layout (ushort units), peak < 30 MB (37.75 MB proven safe in round 2):
//   qkv      [0,        9437184)   4096x2304 bf16; later: x_ln2 [0,3145728),
//                                  hidden chunk [3145728, 9437184)
//   z        [9437184, 12582912)   4096x768 bf16; later winT/woutT overwrite
//   wqkvT    [12582912,14352384)   2304x768 bf16
//   woT      [14352384,14942208)   768x768 bf16
//   winT  -> [9437184, 11796480)   3072 rows x 768 (after W_O gemm)
//   woutT -> [11796480,14155776)   768 rows x 3072 (after W_O gemm)
//   bias_cat fp32 @ byte 29884416 (2304 floats)
extern "C" void kernel_launch(void* const* d_in, const int* in_sizes, int n_in,
                              void* d_out, int out_size, void* d_ws, size_t ws_size,
                              hipStream_t stream) {
    const float* resid_pre = (const float*)d_in[0];
    const float* W_Q  = (const float*)d_in[1];
    const float* b_Q  = (const float*)d_in[2];
    const float* W_K  = (const float*)d_in[3];
    const float* b_K  = (const float*)d_in[4];
    const float* W_V  = (const float*)d_in[5];
    const float* b_V  = (const float*)d_in[6];
    const float* W_O  = (const float*)d_in[7];
    const float* b_O  = (const float*)d_in[8];
    const float* ln1_w = (const float*)d_in[9];
    const float* ln1_b = (const float*)d_in[10];
    const float* ln2_w = (const float*)d_in[11];
    const float* ln2_b = (const float*)d_in[12];
    const float* W_in  = (const float*)d_in[13];
    const float* b_in  = (const float*)d_in[14];
    const float* W_out = (const float*)d_in[15];
    const float* b_out = (const float*)d_in[16];
    float* out = (float*)d_out;

    ushort_t* ws = (ushort_t*)d_ws;
    ushort_t* qkv    = ws;
    ushort_t* zbuf   = ws + 9437184;
    ushort_t* wqkvT  = ws + 12582912;
    ushort_t* woT    = ws + 14352384;
    ushort_t* winT   = ws + 9437184;
    ushort_t* woutT  = ws + 11796480;
    float*    bias_cat = (float*)((char*)d_ws + 29884416);
    ushort_t* x_ln1  = (ushort_t*)d_out;          // d_out as bf16 scratch
    ushort_t* x_ln2  = ws;                        // reuse q region
    ushort_t* hidden = ws + 3145728;              // reuse k|v region
    float*    resid_mid = out;                    // d_out fp32

    dim3 blk(256);

    // --- weight conversion (QKV repack + transposes) ---
    transpose_cvt<<<dim3(12, 1, 12), blk, 0, stream>>>(W_Q, 64, 49152, wqkvT,            768, 49152);
    transpose_cvt<<<dim3(12, 1, 12), blk, 0, stream>>>(W_K, 64, 49152, wqkvT + 589824,   768, 49152);
    transpose_cvt<<<dim3(12, 1, 12), blk, 0, stream>>>(W_V, 64, 49152, wqkvT + 1179648,  768, 49152);
    transpose_cvt<<<dim3(12, 12, 1), blk, 0, stream>>>(W_O, 768, 0, woT, 768, 0);
    hipMemcpyAsync(bias_cat,        b_Q, 768 * 4, hipMemcpyDeviceToDevice, stream);
    hipMemcpyAsync(bias_cat + 768,  b_K, 768 * 4, hipMemcpyDeviceToDevice, stream);
    hipMemcpyAsync(bias_cat + 1536, b_V, 768 * 4, hipMemcpyDeviceToDevice, stream);

    // 1. ln1 -> x_ln1 (bf16, in d_out)
    ln_kernel<<<ROWS, blk, 0, stream>>>(resid_pre, ln1_w, ln1_b, x_ln1);
    // 2. fused QKV projection: [4096,768] @ [768,2304] -> qkv bf16
    mfma_gemm<0><<<dim3(18, 32), blk, 0, stream>>>(x_ln1, D_MODEL, wqkvT, D_MODEL,
                                                   bias_cat, nullptr, qkv, QKV_LD, D_MODEL);
    // 3. attention
    attn_kernel<<<dim3(SEQ / 16, N_HEADS, BATCH), blk, 0, stream>>>(qkv, zbuf);
    // 4. W_O projection + residual -> resid_mid (fp32, d_out)
    mfma_gemm<1><<<dim3(6, 32), blk, 0, stream>>>(zbuf, D_MODEL, woT, D_MODEL,
                                                  b_O, resid_pre, resid_mid, D_MODEL, D_MODEL);
    // --- MLP weight conversion (into dead z/wqkvT region) ---
    transpose_cvt<<<dim3(12, 48, 1), blk, 0, stream>>>(W_in, 3072, 0, winT, 768, 0);
    transpose_cvt<<<dim3(48, 12, 1), blk, 0, stream>>>(W_out, 768, 0, woutT, 3072, 0);
    // 5. ln2 -> x_ln2 (bf16, q region)
    ln_kernel<<<ROWS, blk, 0, stream>>>(resid_mid, ln2_w, ln2_b, x_ln2);
    // 6-7. MLP in 2 row-chunks of 2048
    for (int c = 0; c < 2; ++c) {
        const ushort_t* xc = x_ln2 + (size_t)c * 2048 * D_MODEL;
        float* oc = out + (size_t)c * 2048 * D_MODEL;
        mfma_gemm<2><<<dim3(24, 16), blk, 0, stream>>>(xc, D_MODEL, winT, D_MODEL,
                                                       b_in, nullptr, hidden, D_MLP, D_MODEL);
        mfma_gemm<1><<<dim3(6, 16), blk, 0, stream>>>(hidden, D_MLP, woutT, D_MLP,
                                                      b_out, oc, oc, D_MODEL, D_MLP);
    }
}

// Round 7
// 965.082 us; speedup vs baseline: 5.2900x; 1.1354x over previous
//
#include <hip/hip_runtime.h>
#include <math.h>

typedef unsigned short ushort_t;
typedef __attribute__((ext_vector_type(8))) short bf16x8;
typedef __attribute__((ext_vector_type(4))) float f32x4;

// ---------------- constants ----------------
#define D_MODEL 768
#define N_HEADS 12
#define D_HEAD  64
#define D_MLP   3072
#define BATCH   2
#define SEQ     2048
#define ROWS    (BATCH * SEQ)          // 4096
#define LN_EPS  1e-5f
#define QKV_LD  2304                   // combined q|k|v row stride

// ---------------- bf16 helpers ----------------
__device__ __forceinline__ ushort_t f2bf(float f) {
    unsigned u = __float_as_uint(f);
    u += 0x7fffu + ((u >> 16) & 1u);   // round-to-nearest-even
    return (ushort_t)(u >> 16);
}
__device__ __forceinline__ float bf2f(ushort_t u) {
    return __uint_as_float((unsigned)u << 16);
}

#define GLD16(g, l) __builtin_amdgcn_global_load_lds( \
    (const __attribute__((address_space(1))) void*)(g), \
    (__attribute__((address_space(3))) void*)(l), 16, 0, 0)

// ---------------- LayerNorm (fp32 in -> bf16 out) ----------------
__global__ __launch_bounds__(256) void ln_kernel(const float* __restrict__ x,
                                                 const float* __restrict__ w,
                                                 const float* __restrict__ b,
                                                 ushort_t* __restrict__ y) {
    int row = blockIdx.x;
    const float* xr = x + (size_t)row * D_MODEL;
    float v[3];
    float s = 0.f, sq = 0.f;
#pragma unroll
    for (int u = 0; u < 3; ++u) {
        v[u] = xr[threadIdx.x + u * 256];
        s += v[u];
        sq += v[u] * v[u];
    }
#pragma unroll
    for (int off = 32; off >= 1; off >>= 1) {
        s  += __shfl_xor(s, off);
        sq += __shfl_xor(sq, off);
    }
    __shared__ float ss[4], ssq[4];
    int wave = threadIdx.x >> 6;
    int lane = threadIdx.x & 63;
    if (lane == 0) { ss[wave] = s; ssq[wave] = sq; }
    __syncthreads();
    s = ss[0] + ss[1] + ss[2] + ss[3];
    sq = ssq[0] + ssq[1] + ssq[2] + ssq[3];
    float mean = s * (1.0f / D_MODEL);
    float var = sq * (1.0f / D_MODEL) - mean * mean;
    float rstd = rsqrtf(var + LN_EPS);
    ushort_t* yr = y + (size_t)row * D_MODEL;
#pragma unroll
    for (int u = 0; u < 3; ++u) {
        int idx = threadIdx.x + u * 256;
        yr[idx] = f2bf((v[u] - mean) * rstd * w[idx] + b[idx]);
    }
}

// ---------------- GELU (GPT-2 'new', exp form) ----------------
__device__ __forceinline__ float gelu_new_f(float x) {
    float y2 = -1.5957691216057308f * (x + 0.044715f * x * x * x);
    return x / (1.0f + __expf(y2));
}

// ---------------- tiled transpose + fp32->bf16 convert ----------------
__global__ __launch_bounds__(256) void transpose_cvt(
        const float* __restrict__ in, int in_ld, long in_zs,
        ushort_t* __restrict__ out, int out_ld, long out_zs) {
    __shared__ float T[64][65];
    long ib = (long)blockIdx.z * in_zs;
    long ob = (long)blockIdx.z * out_zs;
    int r0 = blockIdx.x * 64;
    int c0 = blockIdx.y * 64;
    int tr = threadIdx.x >> 4;
    int tc4 = (threadIdx.x & 15) * 4;
#pragma unroll
    for (int i = 0; i < 4; ++i) {
        int r = i * 16 + tr;
        float4 v = *reinterpret_cast<const float4*>(in + ib + (long)(r0 + r) * in_ld + c0 + tc4);
        T[r][tc4 + 0] = v.x; T[r][tc4 + 1] = v.y;
        T[r][tc4 + 2] = v.z; T[r][tc4 + 3] = v.w;
    }
    __syncthreads();
#pragma unroll
    for (int i = 0; i < 4; ++i) {
        int oc = i * 16 + tr;
        ushort4 o;
        o.x = f2bf(T[tc4 + 0][oc]);
        o.y = f2bf(T[tc4 + 1][oc]);
        o.z = f2bf(T[tc4 + 2][oc]);
        o.w = f2bf(T[tc4 + 3][oc]);
        *reinterpret_cast<ushort4*>(out + ob + (long)(c0 + oc) * out_ld + r0 + tc4) = o;
    }
}

// ---------------- bf16 MFMA GEMM (unchanged, passing) ----------------
template <int MODE>
__global__ __launch_bounds__(256) void mfma_gemm(
        const ushort_t* __restrict__ A, int lda,
        const ushort_t* __restrict__ Bt, int ldb,
        const float* __restrict__ bias,
        const float* __restrict__ resid,
        void* __restrict__ C, int cld, int K) {
    __shared__ char As[16384];
    __shared__ char Bs[16384];
    int tid = threadIdx.x;
    int lane = tid & 63, wv = tid >> 6;
    int wr = wv >> 1, wc = wv & 1;
    int l15 = lane & 15, lhi = lane >> 4;
    int m0 = blockIdx.y * 128, n0 = blockIdx.x * 128;

    f32x4 acc[4][4];
#pragma unroll
    for (int i = 0; i < 4; ++i)
#pragma unroll
        for (int j = 0; j < 4; ++j) acc[i][j] = (f32x4)(0.f);

    int srow[4], scol[4];
#pragma unroll
    for (int i = 0; i < 4; ++i) {
        int p = (i * 256 + tid) << 4;
        srow[i] = p >> 7;
        scol[i] = ((p & 127) ^ ((srow[i] & 7) << 4)) >> 1;
    }
    int lbase = wv << 10;

    for (int k0 = 0; k0 < K; k0 += 64) {
#pragma unroll
        for (int i = 0; i < 4; ++i) {
            const ushort_t* ga = A + (size_t)(m0 + srow[i]) * lda + k0 + scol[i];
            GLD16(ga, As + i * 4096 + lbase);
            const ushort_t* gb = Bt + (size_t)(n0 + srow[i]) * ldb + k0 + scol[i];
            GLD16(gb, Bs + i * 4096 + lbase);
        }
        __syncthreads();

        bf16x8 af[4][2], bfr[4][2];
#pragma unroll
        for (int f = 0; f < 4; ++f)
#pragma unroll
            for (int h = 0; h < 2; ++h) {
                int ar = wr * 64 + f * 16 + l15;
                int ac = h * 64 + lhi * 16;
                af[f][h] = *reinterpret_cast<const bf16x8*>(As + ar * 128 + (ac ^ ((ar & 7) << 4)));
                int br = wc * 64 + f * 16 + l15;
                bfr[f][h] = *reinterpret_cast<const bf16x8*>(Bs + br * 128 + (ac ^ ((br & 7) << 4)));
            }
#pragma unroll
        for (int fm = 0; fm < 4; ++fm)
#pragma unroll
            for (int fn = 0; fn < 4; ++fn) {
                acc[fm][fn] = __builtin_amdgcn_mfma_f32_16x16x32_bf16(af[fm][0], bfr[fn][0], acc[fm][fn], 0, 0, 0);
                acc[fm][fn] = __builtin_amdgcn_mfma_f32_16x16x32_bf16(af[fm][1], bfr[fn][1], acc[fm][fn], 0, 0, 0);
            }
        __syncthreads();
    }

#pragma unroll
    for (int fm = 0; fm < 4; ++fm)
#pragma unroll
        for (int fn = 0; fn < 4; ++fn)
#pragma unroll
            for (int i = 0; i < 4; ++i) {
                int m = m0 + wr * 64 + fm * 16 + lhi * 4 + i;
                int n = n0 + wc * 64 + fn * 16 + l15;
                float v = acc[fm][fn][i] + bias[n];
                if (MODE == 0) {
                    ((ushort_t*)C)[(size_t)m * cld + n] = f2bf(v);
                } else if (MODE == 1) {
                    ((float*)C)[(size_t)m * cld + n] = v + resid[(size_t)m * cld + n];
                } else {
                    ((ushort_t*)C)[(size_t)m * cld + n] = f2bf(gelu_new_f(v));
                }
            }
}

// ---------------- wave reductions ----------------
__device__ __forceinline__ float wred_max(float x) {
#pragma unroll
    for (int o = 32; o >= 1; o >>= 1) x = fmaxf(x, __shfl_xor(x, o));
    return x;
}
__device__ __forceinline__ float wred_sum(float x) {
#pragma unroll
    for (int o = 32; o >= 1; o >>= 1) x += __shfl_xor(x, o);
    return x;
}

// ---------------- causal flash attention v2 ----------------
// bf16 K/V in LDS with pad 66 (stride 33 words -> bank advance 1 -> 2-way, free).
// LDS = 2*8448 + 4096 + 4096 = 25088 B -> 6 blocks/CU.
// Reversed q-tile order: heaviest causal blocks launch first.
__global__ __launch_bounds__(256) void attn_kernel(const ushort_t* __restrict__ qkv,
                                                   ushort_t* __restrict__ z) {
    __shared__ ushort_t Ks[64][66];
    __shared__ ushort_t Vs[64][66];
    __shared__ float Qs[16][64];
    __shared__ float Ps[4][4][64];

    int tid = threadIdx.x;
    int wave = tid >> 6, lane = tid & 63;
    int head = blockIdx.y, batch = blockIdx.z;
    int qbase = (gridDim.x - 1 - blockIdx.x) * 16;   // reverse order
    size_t rowb = (size_t)batch * SEQ;
    int hcol = head * 64;

    // stage 16 q rows (bf16 -> fp32, pre-scaled)
    {
        int row = tid >> 4;
        int c4 = (tid & 15) << 2;
        const ushort_t* qp = qkv + (rowb + qbase + row) * QKV_LD + hcol + c4;
        ushort4 qv = *reinterpret_cast<const ushort4*>(qp);
        Qs[row][c4 + 0] = bf2f(qv.x) * 0.125f;
        Qs[row][c4 + 1] = bf2f(qv.y) * 0.125f;
        Qs[row][c4 + 2] = bf2f(qv.z) * 0.125f;
        Qs[row][c4 + 3] = bf2f(qv.w) * 0.125f;
    }

    int w4 = wave * 4;
    int qr = qbase + w4;
    float m0 = -1e30f, m1 = -1e30f, m2 = -1e30f, m3 = -1e30f;
    float l0 = 0, l1 = 0, l2 = 0, l3 = 0;
    float o0 = 0, o1 = 0, o2 = 0, o3 = 0;

    for (int kt = 0; kt < qbase + 16; kt += 64) {
        __syncthreads();
        // stage 64 keys of K and V as bf16 (no unpack): uint4 load + 4 b32 writes
#pragma unroll
        for (int it = 0; it < 2; ++it) {
            int idx = it * 256 + tid;
            int row = idx >> 3;
            int c8 = (idx & 7) << 3;
            const ushort_t* kp = qkv + (rowb + kt + row) * QKV_LD + hcol + 768 + c8;
            const ushort_t* vp = qkv + (rowb + kt + row) * QKV_LD + hcol + 1536 + c8;
            uint4 kw = *reinterpret_cast<const uint4*>(kp);
            uint4 vw = *reinterpret_cast<const uint4*>(vp);
            unsigned* kd = reinterpret_cast<unsigned*>(&Ks[row][c8]);
            unsigned* vd = reinterpret_cast<unsigned*>(&Vs[row][c8]);
            kd[0] = kw.x; kd[1] = kw.y; kd[2] = kw.z; kd[3] = kw.w;
            vd[0] = vw.x; vd[1] = vw.y; vd[2] = vw.z; vd[3] = vw.w;
        }
        __syncthreads();

        // QK^T: lane j <-> key kt+j
        float s0 = 0, s1 = 0, s2 = 0, s3 = 0;
#pragma unroll
        for (int d = 0; d < 64; d += 2) {
            unsigned ku = *reinterpret_cast<const unsigned*>(&Ks[lane][d]);
            float kx = bf2f((ushort_t)(ku & 0xffff));
            float ky = bf2f((ushort_t)(ku >> 16));
            float2 qa = *reinterpret_cast<const float2*>(&Qs[w4 + 0][d]);
            float2 qb = *reinterpret_cast<const float2*>(&Qs[w4 + 1][d]);
            float2 qc = *reinterpret_cast<const float2*>(&Qs[w4 + 2][d]);
            float2 qd = *reinterpret_cast<const float2*>(&Qs[w4 + 3][d]);
            s0 = fmaf(qa.x, kx, s0); s0 = fmaf(qa.y, ky, s0);
            s1 = fmaf(qb.x, kx, s1); s1 = fmaf(qb.y, ky, s1);
            s2 = fmaf(qc.x, kx, s2); s2 = fmaf(qc.y, ky, s2);
            s3 = fmaf(qd.x, kx, s3); s3 = fmaf(qd.y, ky, s3);
        }

        int key = kt + lane;
        {
            float sm = (key <= qr + 0) ? s0 : -1e30f;
            float mn = fmaxf(m0, wred_max(sm));
            float corr = __expf(m0 - mn);
            float p = __expf(sm - mn);
            l0 = l0 * corr + wred_sum(p);
            o0 *= corr; m0 = mn;
            Ps[wave][0][lane] = p;
        }
        {
            float sm = (key <= qr + 1) ? s1 : -1e30f;
            float mn = fmaxf(m1, wred_max(sm));
            float corr = __expf(m1 - mn);
            float p = __expf(sm - mn);
            l1 = l1 * corr + wred_sum(p);
            o1 *= corr; m1 = mn;
            Ps[wave][1][lane] = p;
        }
        {
            float sm = (key <= qr + 2) ? s2 : -1e30f;
            float mn = fmaxf(m2, wred_max(sm));
            float corr = __expf(m2 - mn);
            float p = __expf(sm - mn);
            l2 = l2 * corr + wred_sum(p);
            o2 *= corr; m2 = mn;
            Ps[wave][2][lane] = p;
        }
        {
            float sm = (key <= qr + 3) ? s3 : -1e30f;
            float mn = fmaxf(m3, wred_max(sm));
            float corr = __expf(m3 - mn);
            float p = __expf(sm - mn);
            l3 = l3 * corr + wred_sum(p);
            o3 *= corr; m3 = mn;
            Ps[wave][3][lane] = p;
        }

        // PV: lane d accumulates; V reads conflict-free (2-way), P uniform
#pragma unroll
        for (int j = 0; j < 64; j += 2) {
            float va = bf2f(Vs[j][lane]);
            float vb = bf2f(Vs[j + 1][lane]);
            float2 p0 = *reinterpret_cast<const float2*>(&Ps[wave][0][j]);
            float2 p1 = *reinterpret_cast<const float2*>(&Ps[wave][1][j]);
            float2 p2 = *reinterpret_cast<const float2*>(&Ps[wave][2][j]);
            float2 p3 = *reinterpret_cast<const float2*>(&Ps[wave][3][j]);
            o0 = fmaf(p0.x, va, o0); o0 = fmaf(p0.y, vb, o0);
            o1 = fmaf(p1.x, va, o1); o1 = fmaf(p1.y, vb, o1);
            o2 = fmaf(p2.x, va, o2); o2 = fmaf(p2.y, vb, o2);
            o3 = fmaf(p3.x, va, o3); o3 = fmaf(p3.y, vb, o3);
        }
    }

    z[(rowb + qr + 0) * D_MODEL + hcol + lane] = f2bf(o0 / l0);
    z[(rowb + qr + 1) * D_MODEL + hcol + lane] = f2bf(o1 / l1);
    z[(rowb + qr + 2) * D_MODEL + hcol + lane] = f2bf(o2 / l2);
    z[(rowb + qr + 3) * D_MODEL + hcol + lane] = f2bf(o3 / l3);
}

// ---------------- launch ----------------
extern "C" void kernel_launch(void* const* d_in, const int* in_sizes, int n_in,
                              void* d_out, int out_size, void* d_ws, size_t ws_size,
                              hipStream_t stream) {
    const float* resid_pre = (const float*)d_in[0];
    const float* W_Q  = (const float*)d_in[1];
    const float* b_Q  = (const float*)d_in[2];
    const float* W_K  = (const float*)d_in[3];
    const float* b_K  = (const float*)d_in[4];
    const float* W_V  = (const float*)d_in[5];
    const float* b_V  = (const float*)d_in[6];
    const float* W_O  = (const float*)d_in[7];
    const float* b_O  = (const float*)d_in[8];
    const float* ln1_w = (const float*)d_in[9];
    const float* ln1_b = (const float*)d_in[10];
    const float* ln2_w = (const float*)d_in[11];
    const float* ln2_b = (const float*)d_in[12];
    const float* W_in  = (const float*)d_in[13];
    const float* b_in  = (const float*)d_in[14];
    const float* W_out = (const float*)d_in[15];
    const float* b_out = (const float*)d_in[16];
    float* out = (float*)d_out;

    ushort_t* ws = (ushort_t*)d_ws;
    ushort_t* qkv    = ws;
    ushort_t* zbuf   = ws + 9437184;
    ushort_t* wqkvT  = ws + 12582912;
    ushort_t* woT    = ws + 14352384;
    ushort_t* winT   = ws + 9437184;
    ushort_t* woutT  = ws + 11796480;
    float*    bias_cat = (float*)((char*)d_ws + 29884416);
    ushort_t* x_ln1  = (ushort_t*)d_out;
    ushort_t* x_ln2  = ws;
    ushort_t* hidden = ws + 3145728;
    float*    resid_mid = out;

    dim3 blk(256);

    transpose_cvt<<<dim3(12, 1, 12), blk, 0, stream>>>(W_Q, 64, 49152, wqkvT,            768, 49152);
    transpose_cvt<<<dim3(12, 1, 12), blk, 0, stream>>>(W_K, 64, 49152, wqkvT + 589824,   768, 49152);
    transpose_cvt<<<dim3(12, 1, 12), blk, 0, stream>>>(W_V, 64, 49152, wqkvT + 1179648,  768, 49152);
    transpose_cvt<<<dim3(12, 12, 1), blk, 0, stream>>>(W_O, 768, 0, woT, 768, 0);
    hipMemcpyAsync(bias_cat,        b_Q, 768 * 4, hipMemcpyDeviceToDevice, stream);
    hipMemcpyAsync(bias_cat + 768,  b_K, 768 * 4, hipMemcpyDeviceToDevice, stream);
    hipMemcpyAsync(bias_cat + 1536, b_V, 768 * 4, hipMemcpyDeviceToDevice, stream);

    ln_kernel<<<ROWS, blk, 0, stream>>>(resid_pre, ln1_w, ln1_b, x_ln1);
    mfma_gemm<0><<<dim3(18, 32), blk, 0, stream>>>(x_ln1, D_MODEL, wqkvT, D_MODEL,
                                                   bias_cat, nullptr, qkv, QKV_LD, D_MODEL);
    attn_kernel<<<dim3(SEQ / 16, N_HEADS, BATCH), blk, 0, stream>>>(qkv, zbuf);
    mfma_gemm<1><<<dim3(6, 32), blk, 0, stream>>>(zbuf, D_MODEL, woT, D_MODEL,
                                                  b_O, resid_pre, resid_mid, D_MODEL, D_MODEL);
    transpose_cvt<<<dim3(12, 48, 1), blk, 0, stream>>>(W_in, 3072, 0, winT, 768, 0);
    transpose_cvt<<<dim3(48, 12, 1), blk, 0, stream>>>(W_out, 768, 0, woutT, 3072, 0);
    ln_kernel<<<ROWS, blk, 0, stream>>>(resid_mid, ln2_w, ln2_b, x_ln2);
    for (int c = 0; c < 2; ++c) {
        const ushort_t* xc = x_ln2 + (size_t)c * 2048 * D_MODEL;
        float* oc = out + (size_t)c * 2048 * D_MODEL;
        mfma_gemm<2><<<dim3(24, 16), blk, 0, stream>>>(xc, D_MODEL, winT, D_MODEL,
                                                       b_in, nullptr, hidden, D_MLP, D_MODEL);
        mfma_gemm<1><<<dim3(6, 16), blk, 0, stream>>>(hidden, D_MLP, woutT, D_MLP,
                                                      b_out, oc, oc, D_MODEL, D_MLP);
    }
}

// Round 8
// 446.354 us; speedup vs baseline: 11.4378x; 2.1621x over previous
//
#include <hip/hip_runtime.h>
#include <math.h>

typedef unsigned short ushort_t;
typedef __attribute__((ext_vector_type(8))) short bf16x8;
typedef __attribute__((ext_vector_type(4))) float f32x4;

// ---------------- constants ----------------
#define D_MODEL 768
#define N_HEADS 12
#define D_HEAD  64
#define D_MLP   3072
#define BATCH   2
#define SEQ     2048
#define ROWS    (BATCH * SEQ)          // 4096
#define LN_EPS  1e-5f
#define QKV_LD  2304                   // combined q|k|v row stride

// ---------------- bf16 helpers ----------------
__device__ __forceinline__ ushort_t f2bf(float f) {
    unsigned u = __float_as_uint(f);
    u += 0x7fffu + ((u >> 16) & 1u);   // round-to-nearest-even
    return (ushort_t)(u >> 16);
}
__device__ __forceinline__ float bf2f(ushort_t u) {
    return __uint_as_float((unsigned)u << 16);
}

#define GLD16(g, l) __builtin_amdgcn_global_load_lds( \
    (const __attribute__((address_space(1))) void*)(g), \
    (__attribute__((address_space(3))) void*)(l), 16, 0, 0)

// ---------------- LayerNorm (fp32 in -> bf16 out) ----------------
__global__ __launch_bounds__(256) void ln_kernel(const float* __restrict__ x,
                                                 const float* __restrict__ w,
                                                 const float* __restrict__ b,
                                                 ushort_t* __restrict__ y) {
    int row = blockIdx.x;
    const float* xr = x + (size_t)row * D_MODEL;
    float v[3];
    float s = 0.f, sq = 0.f;
#pragma unroll
    for (int u = 0; u < 3; ++u) {
        v[u] = xr[threadIdx.x + u * 256];
        s += v[u];
        sq += v[u] * v[u];
    }
#pragma unroll
    for (int off = 32; off >= 1; off >>= 1) {
        s  += __shfl_xor(s, off);
        sq += __shfl_xor(sq, off);
    }
    __shared__ float ss[4], ssq[4];
    int wave = threadIdx.x >> 6;
    int lane = threadIdx.x & 63;
    if (lane == 0) { ss[wave] = s; ssq[wave] = sq; }
    __syncthreads();
    s = ss[0] + ss[1] + ss[2] + ss[3];
    sq = ssq[0] + ssq[1] + ssq[2] + ssq[3];
    float mean = s * (1.0f / D_MODEL);
    float var = sq * (1.0f / D_MODEL) - mean * mean;
    float rstd = rsqrtf(var + LN_EPS);
    ushort_t* yr = y + (size_t)row * D_MODEL;
#pragma unroll
    for (int u = 0; u < 3; ++u) {
        int idx = threadIdx.x + u * 256;
        yr[idx] = f2bf((v[u] - mean) * rstd * w[idx] + b[idx]);
    }
}

// ---------------- GELU (GPT-2 'new', exp form) ----------------
__device__ __forceinline__ float gelu_new_f(float x) {
    float y2 = -1.5957691216057308f * (x + 0.044715f * x * x * x);
    return x / (1.0f + __expf(y2));
}

// ---------------- tiled transpose + fp32->bf16 convert ----------------
__global__ __launch_bounds__(256) void transpose_cvt(
        const float* __restrict__ in, int in_ld, long in_zs,
        ushort_t* __restrict__ out, int out_ld, long out_zs) {
    __shared__ float T[64][65];
    long ib = (long)blockIdx.z * in_zs;
    long ob = (long)blockIdx.z * out_zs;
    int r0 = blockIdx.x * 64;
    int c0 = blockIdx.y * 64;
    int tr = threadIdx.x >> 4;
    int tc4 = (threadIdx.x & 15) * 4;
#pragma unroll
    for (int i = 0; i < 4; ++i) {
        int r = i * 16 + tr;
        float4 v = *reinterpret_cast<const float4*>(in + ib + (long)(r0 + r) * in_ld + c0 + tc4);
        T[r][tc4 + 0] = v.x; T[r][tc4 + 1] = v.y;
        T[r][tc4 + 2] = v.z; T[r][tc4 + 3] = v.w;
    }
    __syncthreads();
#pragma unroll
    for (int i = 0; i < 4; ++i) {
        int oc = i * 16 + tr;
        ushort4 o;
        o.x = f2bf(T[tc4 + 0][oc]);
        o.y = f2bf(T[tc4 + 1][oc]);
        o.z = f2bf(T[tc4 + 2][oc]);
        o.w = f2bf(T[tc4 + 3][oc]);
        *reinterpret_cast<ushort4*>(out + ob + (long)(c0 + oc) * out_ld + r0 + tc4) = o;
    }
}

// ---------------- bf16 MFMA GEMM (unchanged, passing) ----------------
template <int MODE>
__global__ __launch_bounds__(256) void mfma_gemm(
        const ushort_t* __restrict__ A, int lda,
        const ushort_t* __restrict__ Bt, int ldb,
        const float* __restrict__ bias,
        const float* __restrict__ resid,
        void* __restrict__ C, int cld, int K) {
    __shared__ char As[16384];
    __shared__ char Bs[16384];
    int tid = threadIdx.x;
    int lane = tid & 63, wv = tid >> 6;
    int wr = wv >> 1, wc = wv & 1;
    int l15 = lane & 15, lhi = lane >> 4;
    int m0 = blockIdx.y * 128, n0 = blockIdx.x * 128;

    f32x4 acc[4][4];
#pragma unroll
    for (int i = 0; i < 4; ++i)
#pragma unroll
        for (int j = 0; j < 4; ++j) acc[i][j] = (f32x4)(0.f);

    int srow[4], scol[4];
#pragma unroll
    for (int i = 0; i < 4; ++i) {
        int p = (i * 256 + tid) << 4;
        srow[i] = p >> 7;
        scol[i] = ((p & 127) ^ ((srow[i] & 7) << 4)) >> 1;
    }
    int lbase = wv << 10;

    for (int k0 = 0; k0 < K; k0 += 64) {
#pragma unroll
        for (int i = 0; i < 4; ++i) {
            const ushort_t* ga = A + (size_t)(m0 + srow[i]) * lda + k0 + scol[i];
            GLD16(ga, As + i * 4096 + lbase);
            const ushort_t* gb = Bt + (size_t)(n0 + srow[i]) * ldb + k0 + scol[i];
            GLD16(gb, Bs + i * 4096 + lbase);
        }
        __syncthreads();

        bf16x8 af[4][2], bfr[4][2];
#pragma unroll
        for (int f = 0; f < 4; ++f)
#pragma unroll
            for (int h = 0; h < 2; ++h) {
                int ar = wr * 64 + f * 16 + l15;
                int ac = h * 64 + lhi * 16;
                af[f][h] = *reinterpret_cast<const bf16x8*>(As + ar * 128 + (ac ^ ((ar & 7) << 4)));
                int br = wc * 64 + f * 16 + l15;
                bfr[f][h] = *reinterpret_cast<const bf16x8*>(Bs + br * 128 + (ac ^ ((br & 7) << 4)));
            }
#pragma unroll
        for (int fm = 0; fm < 4; ++fm)
#pragma unroll
            for (int fn = 0; fn < 4; ++fn) {
                acc[fm][fn] = __builtin_amdgcn_mfma_f32_16x16x32_bf16(af[fm][0], bfr[fn][0], acc[fm][fn], 0, 0, 0);
                acc[fm][fn] = __builtin_amdgcn_mfma_f32_16x16x32_bf16(af[fm][1], bfr[fn][1], acc[fm][fn], 0, 0, 0);
            }
        __syncthreads();
    }

#pragma unroll
    for (int fm = 0; fm < 4; ++fm)
#pragma unroll
        for (int fn = 0; fn < 4; ++fn)
#pragma unroll
            for (int i = 0; i < 4; ++i) {
                int m = m0 + wr * 64 + fm * 16 + lhi * 4 + i;
                int n = n0 + wc * 64 + fn * 16 + l15;
                float v = acc[fm][fn][i] + bias[n];
                if (MODE == 0) {
                    ((ushort_t*)C)[(size_t)m * cld + n] = f2bf(v);
                } else if (MODE == 1) {
                    ((float*)C)[(size_t)m * cld + n] = v + resid[(size_t)m * cld + n];
                } else {
                    ((ushort_t*)C)[(size_t)m * cld + n] = f2bf(gelu_new_f(v));
                }
            }
}

// ---------------- MFMA causal flash attention ----------------
// Block: 4 waves x 16 q rows = 64 q rows. KV tile = 64 keys.
// Fragment layouts identical to the hardware-validated mfma_gemm:
//   A-frag: lane(l15=row, lhi) holds k = h*32 + lhi*8 + 0..7
//   B-frag: lane(l15=col-row-of-Bt, lhi) same k
//   C/D   : col = l15, row = lhi*4 + i
// LDS tiles are [row][128B] with byte-XOR swizzle ((row&7)<<4), both sides.
// K staged row-major via global_load_lds (pre-swizzled source, GEMM pattern).
// V staged TRANSPOSED (VT[d][key]) via per-lane b16 writes (2-way, free).
// P round-trips through per-wave swizzled LDS to become the PV A-frag.
__global__ __launch_bounds__(256) void attn_mfma(const ushort_t* __restrict__ qkv,
                                                 ushort_t* __restrict__ z) {
    __shared__ char Ks[8192];
    __shared__ char VT[8192];
    __shared__ char Ps[8192];   // 4 waves x [16][64] bf16 (swizzled)

    int tid = threadIdx.x;
    int lane = tid & 63, wq = tid >> 6;
    int l15 = lane & 15, lhi = lane >> 4;
    int head = blockIdx.y, batch = blockIdx.z;
    int qbase = ((int)gridDim.x - 1 - (int)blockIdx.x) * 64;   // reversed: heavy first
    size_t rowb = (size_t)batch * SEQ;
    int hcol = head * 64;
    int qb0 = qbase + wq * 16;          // this wave's first q row

    // Q A-fragments, held in registers for the whole kernel
    bf16x8 qf[2];
    {
        const ushort_t* qp = qkv + (rowb + qb0 + l15) * QKV_LD + hcol;
        qf[0] = *reinterpret_cast<const bf16x8*>(qp + lhi * 8);
        qf[1] = *reinterpret_cast<const bf16x8*>(qp + 32 + lhi * 8);
    }

    float mrow[4], lrow[4];
    f32x4 o[4];
#pragma unroll
    for (int i = 0; i < 4; ++i) { mrow[i] = -1e30f; lrow[i] = 0.f; o[i] = (f32x4)(0.f); }

    // K staging geometry (pre-swizzled source, like mfma_gemm)
    int srow[2], scol[2];
#pragma unroll
    for (int i = 0; i < 2; ++i) {
        int p = (i * 256 + tid) << 4;
        srow[i] = p >> 7;
        scol[i] = ((p & 127) ^ ((srow[i] & 7) << 4)) >> 1;
    }
    char* myPs = Ps + wq * 2048;
    int ntiles = qbase >> 6;            // full tiles; tile ntiles is the masked one

    for (int t = 0; t <= ntiles; ++t) {
        int kt = t << 6;
        __syncthreads();                 // previous tile fully consumed
        // --- stage K (row-major, swizzled dest via pre-swizzled source) ---
#pragma unroll
        for (int i = 0; i < 2; ++i) {
            const ushort_t* gk = qkv + (rowb + kt + srow[i]) * QKV_LD + hcol + 768 + scol[i];
            GLD16(gk, Ks + i * 4096 + (wq << 10));
        }
        // --- stage V transposed: lane = key, wave owns d-slice wq*16..+15 ---
        {
            const ushort_t* vp = qkv + (rowb + kt + lane) * QKV_LD + hcol + 1536 + wq * 16;
#pragma unroll
            for (int u = 0; u < 2; ++u) {
                uint4 vv = *reinterpret_cast<const uint4*>(vp + u * 8);
                int d0 = wq * 16 + u * 8;          // d0 % 8 == 0
                unsigned arr[4] = {vv.x, vv.y, vv.z, vv.w};
#pragma unroll
                for (int e2 = 0; e2 < 4; ++e2) {
                    int e = e2 * 2;                 // d&7 == e (and e+1)
                    *(ushort_t*)(VT + (d0 + e) * 128 + ((lane << 1) ^ (e << 4))) =
                        (ushort_t)(arr[e2] & 0xffff);
                    *(ushort_t*)(VT + (d0 + e + 1) * 128 + ((lane << 1) ^ ((e + 1) << 4))) =
                        (ushort_t)(arr[e2] >> 16);
                }
            }
        }
        __syncthreads();                 // staging (incl. global_load_lds) complete

        // --- S = Q K^T : 8 MFMAs, S[q 16][key 64] in 4 frags ---
        f32x4 s[4];
#pragma unroll
        for (int f = 0; f < 4; ++f) s[f] = (f32x4)(0.f);
#pragma unroll
        for (int h = 0; h < 2; ++h)
#pragma unroll
            for (int f = 0; f < 4; ++f) {
                int kr = f * 16 + l15;
                bf16x8 kf = *reinterpret_cast<const bf16x8*>(
                    Ks + kr * 128 + ((h * 64 + lhi * 16) ^ ((kr & 7) << 4)));
                s[f] = __builtin_amdgcn_mfma_f32_16x16x32_bf16(qf[h], kf, s[f], 0, 0, 0);
            }

        bool lastT = (t == ntiles);
        // --- online softmax; rows q = qb0 + lhi*4 + i, cols key = kt + f*16 + l15 ---
#pragma unroll
        for (int i = 0; i < 4; ++i) {
            int q = qb0 + lhi * 4 + i;
            float sv[4];
#pragma unroll
            for (int f = 0; f < 4; ++f) {
                float x = s[f][i] * 0.125f;
                if (lastT && (kt + f * 16 + l15 > q)) x = -1e30f;
                sv[f] = x;
            }
            float tm = fmaxf(fmaxf(sv[0], sv[1]), fmaxf(sv[2], sv[3]));
#pragma unroll
            for (int ofs = 1; ofs <= 8; ofs <<= 1) tm = fmaxf(tm, __shfl_xor(tm, ofs));
            float mn = fmaxf(mrow[i], tm);
            float corr = __expf(mrow[i] - mn);
            mrow[i] = mn;
            float p0 = __expf(sv[0] - mn), p1 = __expf(sv[1] - mn);
            float p2 = __expf(sv[2] - mn), p3 = __expf(sv[3] - mn);
            float su = p0 + p1 + p2 + p3;
#pragma unroll
            for (int ofs = 1; ofs <= 8; ofs <<= 1) su += __shfl_xor(su, ofs);
            lrow[i] = lrow[i] * corr + su;
#pragma unroll
            for (int fn = 0; fn < 4; ++fn) o[fn][i] *= corr;
            // write P (bf16) to per-wave swizzled LDS
            int prow = lhi * 4 + i;
            char* pr = myPs + prow * 128;
            int sw = (prow & 7) << 4;
            *(ushort_t*)(pr + (((0 * 16 + l15) << 1) ^ sw)) = f2bf(p0);
            *(ushort_t*)(pr + (((1 * 16 + l15) << 1) ^ sw)) = f2bf(p1);
            *(ushort_t*)(pr + (((2 * 16 + l15) << 1) ^ sw)) = f2bf(p2);
            *(ushort_t*)(pr + (((3 * 16 + l15) << 1) ^ sw)) = f2bf(p3);
        }

        // --- PV: o[q][d] += P[q][key] V[key][d], 8 MFMAs ---
#pragma unroll
        for (int h = 0; h < 2; ++h) {
            bf16x8 pa = *reinterpret_cast<const bf16x8*>(
                myPs + l15 * 128 + ((h * 64 + lhi * 16) ^ ((l15 & 7) << 4)));
#pragma unroll
            for (int fn = 0; fn < 4; ++fn) {
                int dr = fn * 16 + l15;
                bf16x8 vf = *reinterpret_cast<const bf16x8*>(
                    VT + dr * 128 + ((h * 64 + lhi * 16) ^ ((dr & 7) << 4)));
                o[fn] = __builtin_amdgcn_mfma_f32_16x16x32_bf16(pa, vf, o[fn], 0, 0, 0);
            }
        }
    }

    // --- epilogue: z[q][d] = o/l ---
#pragma unroll
    for (int i = 0; i < 4; ++i) {
        float inv = 1.0f / lrow[i];
        size_t zr = (rowb + qb0 + lhi * 4 + i) * D_MODEL + hcol;
#pragma unroll
        for (int fn = 0; fn < 4; ++fn)
            z[zr + fn * 16 + l15] = f2bf(o[fn][i] * inv);
    }
}

// ---------------- launch ----------------
extern "C" void kernel_launch(void* const* d_in, const int* in_sizes, int n_in,
                              void* d_out, int out_size, void* d_ws, size_t ws_size,
                              hipStream_t stream) {
    const float* resid_pre = (const float*)d_in[0];
    const float* W_Q  = (const float*)d_in[1];
    const float* b_Q  = (const float*)d_in[2];
    const float* W_K  = (const float*)d_in[3];
    const float* b_K  = (const float*)d_in[4];
    const float* W_V  = (const float*)d_in[5];
    const float* b_V  = (const float*)d_in[6];
    const float* W_O  = (const float*)d_in[7];
    const float* b_O  = (const float*)d_in[8];
    const float* ln1_w = (const float*)d_in[9];
    const float* ln1_b = (const float*)d_in[10];
    const float* ln2_w = (const float*)d_in[11];
    const float* ln2_b = (const float*)d_in[12];
    const float* W_in  = (const float*)d_in[13];
    const float* b_in  = (const float*)d_in[14];
    const float* W_out = (const float*)d_in[15];
    const float* b_out = (const float*)d_in[16];
    float* out = (float*)d_out;

    ushort_t* ws = (ushort_t*)d_ws;
    ushort_t* qkv    = ws;
    ushort_t* zbuf   = ws + 9437184;
    ushort_t* wqkvT  = ws + 12582912;
    ushort_t* woT    = ws + 14352384;
    ushort_t* winT   = ws + 9437184;
    ushort_t* woutT  = ws + 11796480;
    float*    bias_cat = (float*)((char*)d_ws + 29884416);
    ushort_t* x_ln1  = (ushort_t*)d_out;
    ushort_t* x_ln2  = ws;
    ushort_t* hidden = ws + 3145728;
    float*    resid_mid = out;

    dim3 blk(256);

    transpose_cvt<<<dim3(12, 1, 12), blk, 0, stream>>>(W_Q, 64, 49152, wqkvT,            768, 49152);
    transpose_cvt<<<dim3(12, 1, 12), blk, 0, stream>>>(W_K, 64, 49152, wqkvT + 589824,   768, 49152);
    transpose_cvt<<<dim3(12, 1, 12), blk, 0, stream>>>(W_V, 64, 49152, wqkvT + 1179648,  768, 49152);
    transpose_cvt<<<dim3(12, 12, 1), blk, 0, stream>>>(W_O, 768, 0, woT, 768, 0);
    hipMemcpyAsync(bias_cat,        b_Q, 768 * 4, hipMemcpyDeviceToDevice, stream);
    hipMemcpyAsync(bias_cat + 768,  b_K, 768 * 4, hipMemcpyDeviceToDevice, stream);
    hipMemcpyAsync(bias_cat + 1536, b_V, 768 * 4, hipMemcpyDeviceToDevice, stream);

    ln_kernel<<<ROWS, blk, 0, stream>>>(resid_pre, ln1_w, ln1_b, x_ln1);
    mfma_gemm<0><<<dim3(18, 32), blk, 0, stream>>>(x_ln1, D_MODEL, wqkvT, D_MODEL,
                                                   bias_cat, nullptr, qkv, QKV_LD, D_MODEL);
    attn_mfma<<<dim3(SEQ / 64, N_HEADS, BATCH), blk, 0, stream>>>(qkv, zbuf);
    mfma_gemm<1><<<dim3(6, 32), blk, 0, stream>>>(zbuf, D_MODEL, woT, D_MODEL,
                                                  b_O, resid_pre, resid_mid, D_MODEL, D_MODEL);
    transpose_cvt<<<dim3(12, 48, 1), blk, 0, stream>>>(W_in, 3072, 0, winT, 768, 0);
    transpose_cvt<<<dim3(48, 12, 1), blk, 0, stream>>>(W_out, 768, 0, woutT, 3072, 0);
    ln_kernel<<<ROWS, blk, 0, stream>>>(resid_mid, ln2_w, ln2_b, x_ln2);
    for (int c = 0; c < 2; ++c) {
        const ushort_t* xc = x_ln2 + (size_t)c * 2048 * D_MODEL;
        float* oc = out + (size_t)c * 2048 * D_MODEL;
        mfma_gemm<2><<<dim3(24, 16), blk, 0, stream>>>(xc, D_MODEL, winT, D_MODEL,
                                                       b_in, nullptr, hidden, D_MLP, D_MODEL);
        mfma_gemm<1><<<dim3(6, 16), blk, 0, stream>>>(hidden, D_MLP, woutT, D_MLP,
                                                      b_out, oc, oc, D_MODEL, D_MLP);
    }
}

// Round 10
// 373.235 us; speedup vs baseline: 13.6786x; 1.1959x over previous
//
#include <hip/hip_runtime.h>
#include <math.h>

typedef unsigned short ushort_t;
typedef __attribute__((ext_vector_type(8))) short bf16x8;
typedef __attribute__((ext_vector_type(4))) float f32x4;

// ---------------- constants ----------------
#define D_MODEL 768
#define N_HEADS 12
#define D_HEAD  64
#define D_MLP   3072
#define BATCH   2
#define SEQ     2048
#define ROWS    (BATCH * SEQ)          // 4096
#define LN_EPS  1e-5f
#define QKV_LD  2304                   // combined q|k|v row stride

// ---------------- bf16 helpers ----------------
__device__ __forceinline__ ushort_t f2bf(float f) {
    unsigned u = __float_as_uint(f);
    u += 0x7fffu + ((u >> 16) & 1u);   // round-to-nearest-even
    return (ushort_t)(u >> 16);
}
__device__ __forceinline__ float bf2f(ushort_t u) {
    return __uint_as_float((unsigned)u << 16);
}

#define GLD16(g, l) __builtin_amdgcn_global_load_lds( \
    (const __attribute__((address_space(1))) void*)(g), \
    (__attribute__((address_space(3))) void*)(l), 16, 0, 0)

// ---------------- LayerNorm (fp32 in -> bf16 out) ----------------
__global__ __launch_bounds__(256) void ln_kernel(const float* __restrict__ x,
                                                 const float* __restrict__ w,
                                                 const float* __restrict__ b,
                                                 ushort_t* __restrict__ y) {
    int row = blockIdx.x;
    const float* xr = x + (size_t)row * D_MODEL;
    float v[3];
    float s = 0.f, sq = 0.f;
#pragma unroll
    for (int u = 0; u < 3; ++u) {
        v[u] = xr[threadIdx.x + u * 256];
        s += v[u];
        sq += v[u] * v[u];
    }
#pragma unroll
    for (int off = 32; off >= 1; off >>= 1) {
        s  += __shfl_xor(s, off);
        sq += __shfl_xor(sq, off);
    }
    __shared__ float ss[4], ssq[4];
    int wave = threadIdx.x >> 6;
    int lane = threadIdx.x & 63;
    if (lane == 0) { ss[wave] = s; ssq[wave] = sq; }
    __syncthreads();
    s = ss[0] + ss[1] + ss[2] + ss[3];
    sq = ssq[0] + ssq[1] + ssq[2] + ssq[3];
    float mean = s * (1.0f / D_MODEL);
    float var = sq * (1.0f / D_MODEL) - mean * mean;
    float rstd = rsqrtf(var + LN_EPS);
    ushort_t* yr = y + (size_t)row * D_MODEL;
#pragma unroll
    for (int u = 0; u < 3; ++u) {
        int idx = threadIdx.x + u * 256;
        yr[idx] = f2bf((v[u] - mean) * rstd * w[idx] + b[idx]);
    }
}

// ---------------- GELU (GPT-2 'new', exp form) ----------------
__device__ __forceinline__ float gelu_new_f(float x) {
    float y2 = -1.5957691216057308f * (x + 0.044715f * x * x * x);
    return x / (1.0f + __expf(y2));
}

// ---------------- transpose tile (device fn) ----------------
__device__ __forceinline__ void do_transpose(const float* __restrict__ in, int in_ld, long in_zs,
                                             ushort_t* __restrict__ out, int out_ld, long out_zs,
                                             int bx, int by, int bz) {
    __shared__ float T[64][65];
    long ib = (long)bz * in_zs;
    long ob = (long)bz * out_zs;
    int r0 = bx * 64;
    int c0 = by * 64;
    int tr = threadIdx.x >> 4;
    int tc4 = (threadIdx.x & 15) * 4;
#pragma unroll
    for (int i = 0; i < 4; ++i) {
        int r = i * 16 + tr;
        float4 v = *reinterpret_cast<const float4*>(in + ib + (long)(r0 + r) * in_ld + c0 + tc4);
        T[r][tc4 + 0] = v.x; T[r][tc4 + 1] = v.y;
        T[r][tc4 + 2] = v.z; T[r][tc4 + 3] = v.w;
    }
    __syncthreads();
#pragma unroll
    for (int i = 0; i < 4; ++i) {
        int oc = i * 16 + tr;
        ushort4 o;
        o.x = f2bf(T[tc4 + 0][oc]);
        o.y = f2bf(T[tc4 + 1][oc]);
        o.z = f2bf(T[tc4 + 2][oc]);
        o.w = f2bf(T[tc4 + 3][oc]);
        *reinterpret_cast<ushort4*>(out + ob + (long)(c0 + oc) * out_ld + r0 + tc4) = o;
    }
}

// ---------------- fused weight prep: 6 transposes + bias concat ----------------
__global__ __launch_bounds__(256) void prep_kernel(
        const float* __restrict__ WQ, const float* __restrict__ WK,
        const float* __restrict__ WV, const float* __restrict__ WO,
        const float* __restrict__ Win, const float* __restrict__ Wout,
        const float* __restrict__ bQ, const float* __restrict__ bK,
        const float* __restrict__ bV,
        ushort_t* __restrict__ wqkvT, ushort_t* __restrict__ woT,
        ushort_t* __restrict__ winT, ushort_t* __restrict__ woutT,
        float* __restrict__ bias_cat) {
    int id = blockIdx.x;
    if (id < 432) {                       // W_Q/W_K/W_V: [12 heads][768][64] -> [2304][768]
        int j = id / 144, r = id % 144;
        const float* src = (j == 0) ? WQ : (j == 1) ? WK : WV;
        do_transpose(src, 64, 49152, wqkvT + j * 589824, 768, 49152, r % 12, 0, r / 12);
    } else if (id < 576) {                // W_O [768][768] -> [768][768]^T
        int r = id - 432;
        do_transpose(WO, 768, 0, woT, 768, 0, r % 12, r / 12, 0);
    } else if (id < 1152) {               // W_in [768][3072] -> [3072][768]
        int r = id - 576;
        do_transpose(Win, 3072, 0, winT, 768, 0, r % 12, r / 12, 0);
    } else if (id < 1728) {               // W_out [3072][768] -> [768][3072]
        int r = id - 1152;
        do_transpose(Wout, 768, 0, woutT, 3072, 0, r % 48, r / 48, 0);
    } else {                              // bias concat
        for (int i = threadIdx.x; i < 768; i += 256) {
            bias_cat[i] = bQ[i];
            bias_cat[768 + i] = bK[i];
            bias_cat[1536 + i] = bV[i];
        }
    }
}

// ---------------- bf16 MFMA GEMM ----------------
// MODE 0: C bf16 = acc + bias
// MODE 1: C fp32 = acc + bias + resid   (resid may alias C)
// MODE 2: C bf16 = gelu(acc + bias)
// MODE 3: C fp32 += acc                 (accumulate in place, no bias)
template <int MODE>
__global__ __launch_bounds__(256) void mfma_gemm(
        const ushort_t* __restrict__ A, int lda,
        const ushort_t* __restrict__ Bt, int ldb,
        const float* __restrict__ bias,
        const float* __restrict__ resid,
        void* __restrict__ C, int cld, int K) {
    __shared__ char As[16384];
    __shared__ char Bs[16384];
    int tid = threadIdx.x;
    int lane = tid & 63, wv = tid >> 6;
    int wr = wv >> 1, wc = wv & 1;
    int l15 = lane & 15, lhi = lane >> 4;
    int m0 = blockIdx.y * 128, n0 = blockIdx.x * 128;

    f32x4 acc[4][4];
#pragma unroll
    for (int i = 0; i < 4; ++i)
#pragma unroll
        for (int j = 0; j < 4; ++j) acc[i][j] = (f32x4)(0.f);

    int srow[4], scol[4];
#pragma unroll
    for (int i = 0; i < 4; ++i) {
        int p = (i * 256 + tid) << 4;
        srow[i] = p >> 7;
        scol[i] = ((p & 127) ^ ((srow[i] & 7) << 4)) >> 1;
    }
    int lbase = wv << 10;

    for (int k0 = 0; k0 < K; k0 += 64) {
#pragma unroll
        for (int i = 0; i < 4; ++i) {
            const ushort_t* ga = A + (size_t)(m0 + srow[i]) * lda + k0 + scol[i];
            GLD16(ga, As + i * 4096 + lbase);
            const ushort_t* gb = Bt + (size_t)(n0 + srow[i]) * ldb + k0 + scol[i];
            GLD16(gb, Bs + i * 4096 + lbase);
        }
        __syncthreads();

        bf16x8 af[4][2], bfr[4][2];
#pragma unroll
        for (int f = 0; f < 4; ++f)
#pragma unroll
            for (int h = 0; h < 2; ++h) {
                int ar = wr * 64 + f * 16 + l15;
                int ac = h * 64 + lhi * 16;
                af[f][h] = *reinterpret_cast<const bf16x8*>(As + ar * 128 + (ac ^ ((ar & 7) << 4)));
                int br = wc * 64 + f * 16 + l15;
                bfr[f][h] = *reinterpret_cast<const bf16x8*>(Bs + br * 128 + (ac ^ ((br & 7) << 4)));
            }
#pragma unroll
        for (int fm = 0; fm < 4; ++fm)
#pragma unroll
            for (int fn = 0; fn < 4; ++fn) {
                acc[fm][fn] = __builtin_amdgcn_mfma_f32_16x16x32_bf16(af[fm][0], bfr[fn][0], acc[fm][fn], 0, 0, 0);
                acc[fm][fn] = __builtin_amdgcn_mfma_f32_16x16x32_bf16(af[fm][1], bfr[fn][1], acc[fm][fn], 0, 0, 0);
            }
        __syncthreads();
    }

#pragma unroll
    for (int fm = 0; fm < 4; ++fm)
#pragma unroll
        for (int fn = 0; fn < 4; ++fn)
#pragma unroll
            for (int i = 0; i < 4; ++i) {
                int m = m0 + wr * 64 + fm * 16 + lhi * 4 + i;
                int n = n0 + wc * 64 + fn * 16 + l15;
                float v = acc[fm][fn][i];
                if (MODE != 3) v += bias[n];
                if (MODE == 0) {
                    ((ushort_t*)C)[(size_t)m * cld + n] = f2bf(v);
                } else if (MODE == 1) {
                    ((float*)C)[(size_t)m * cld + n] = v + resid[(size_t)m * cld + n];
                } else if (MODE == 2) {
                    ((ushort_t*)C)[(size_t)m * cld + n] = f2bf(gelu_new_f(v));
                } else {
                    ((float*)C)[(size_t)m * cld + n] += v;
                }
            }
}

// ---------------- MFMA causal flash attention, pair-balanced ----------------
// grid (16, 12, 2): block p handles q-tile (31-p) then q-tile p -> uniform 33
// kv-tile-steps per block. z is written IN-PLACE into qkv's q slot (stride
// QKV_LD): each block reads its own q rows before writing them; K/V columns
// (768+) are never written.
__global__ __launch_bounds__(256) void attn_mfma(ushort_t* __restrict__ qkv) {
    __shared__ char Ks[8192];
    __shared__ char VT[8192];
    __shared__ char Ps[8192];   // 4 waves x [16][64] bf16 (swizzled)

    int tid = threadIdx.x;
    int lane = tid & 63, wq = tid >> 6;
    int l15 = lane & 15, lhi = lane >> 4;
    int head = blockIdx.y, batch = blockIdx.z;
    size_t rowb = (size_t)batch * SEQ;
    int hcol = head * 64;

    int srow[2], scol[2];
#pragma unroll
    for (int i = 0; i < 2; ++i) {
        int p = (i * 256 + tid) << 4;
        srow[i] = p >> 7;
        scol[i] = ((p & 127) ^ ((srow[i] & 7) << 4)) >> 1;
    }
    char* myPs = Ps + wq * 2048;

    for (int hh = 0; hh < 2; ++hh) {
        int qt = hh ? (int)blockIdx.x : (31 - (int)blockIdx.x);   // heavy first
        int qbase = qt << 6;
        int qb0 = qbase + wq * 16;

        bf16x8 qf[2];
        {
            const ushort_t* qp = qkv + (rowb + qb0 + l15) * QKV_LD + hcol;
            qf[0] = *reinterpret_cast<const bf16x8*>(qp + lhi * 8);
            qf[1] = *reinterpret_cast<const bf16x8*>(qp + 32 + lhi * 8);
        }

        float mrow[4], lrow[4];
        f32x4 o[4];
#pragma unroll
        for (int i = 0; i < 4; ++i) { mrow[i] = -1e30f; lrow[i] = 0.f; o[i] = (f32x4)(0.f); }

        for (int t = 0; t <= qt; ++t) {
            int kt = t << 6;
            __syncthreads();
#pragma unroll
            for (int i = 0; i < 2; ++i) {
                const ushort_t* gk = qkv + (rowb + kt + srow[i]) * QKV_LD + hcol + 768 + scol[i];
                GLD16(gk, Ks + i * 4096 + (wq << 10));
            }
            {
                const ushort_t* vp = qkv + (rowb + kt + lane) * QKV_LD + hcol + 1536 + wq * 16;
#pragma unroll
                for (int u = 0; u < 2; ++u) {
                    uint4 vv = *reinterpret_cast<const uint4*>(vp + u * 8);
                    int d0 = wq * 16 + u * 8;
                    unsigned arr[4] = {vv.x, vv.y, vv.z, vv.w};
#pragma unroll
                    for (int e2 = 0; e2 < 4; ++e2) {
                        int e = e2 * 2;
                        *(ushort_t*)(VT + (d0 + e) * 128 + ((lane << 1) ^ (e << 4))) =
                            (ushort_t)(arr[e2] & 0xffff);
                        *(ushort_t*)(VT + (d0 + e + 1) * 128 + ((lane << 1) ^ ((e + 1) << 4))) =
                            (ushort_t)(arr[e2] >> 16);
                    }
                }
            }
            __syncthreads();

            f32x4 s[4];
#pragma unroll
            for (int f = 0; f < 4; ++f) s[f] = (f32x4)(0.f);
#pragma unroll
            for (int h = 0; h < 2; ++h)
#pragma unroll
                for (int f = 0; f < 4; ++f) {
                    int kr = f * 16 + l15;
                    bf16x8 kf = *reinterpret_cast<const bf16x8*>(
                        Ks + kr * 128 + ((h * 64 + lhi * 16) ^ ((kr & 7) << 4)));
                    s[f] = __builtin_amdgcn_mfma_f32_16x16x32_bf16(qf[h], kf, s[f], 0, 0, 0);
                }

            bool lastT = (t == qt);
#pragma unroll
            for (int i = 0; i < 4; ++i) {
                int q = qb0 + lhi * 4 + i;
                float sv[4];
#pragma unroll
                for (int f = 0; f < 4; ++f) {
                    float x = s[f][i] * 0.125f;
                    if (lastT && (kt + f * 16 + l15 > q)) x = -1e30f;
                    sv[f] = x;
                }
                float tm = fmaxf(fmaxf(sv[0], sv[1]), fmaxf(sv[2], sv[3]));
#pragma unroll
                for (int ofs = 1; ofs <= 8; ofs <<= 1) tm = fmaxf(tm, __shfl_xor(tm, ofs));
                float mn = fmaxf(mrow[i], tm);
                float corr = __expf(mrow[i] - mn);
                mrow[i] = mn;
                float p0 = __expf(sv[0] - mn), p1 = __expf(sv[1] - mn);
                float p2 = __expf(sv[2] - mn), p3 = __expf(sv[3] - mn);
                float su = p0 + p1 + p2 + p3;
#pragma unroll
                for (int ofs = 1; ofs <= 8; ofs <<= 1) su += __shfl_xor(su, ofs);
                lrow[i] = lrow[i] * corr + su;
#pragma unroll
                for (int fn = 0; fn < 4; ++fn) o[fn][i] *= corr;
                int prow = lhi * 4 + i;
                char* pr = myPs + prow * 128;
                int sw = (prow & 7) << 4;
                *(ushort_t*)(pr + (((0 * 16 + l15) << 1) ^ sw)) = f2bf(p0);
                *(ushort_t*)(pr + (((1 * 16 + l15) << 1) ^ sw)) = f2bf(p1);
                *(ushort_t*)(pr + (((2 * 16 + l15) << 1) ^ sw)) = f2bf(p2);
                *(ushort_t*)(pr + (((3 * 16 + l15) << 1) ^ sw)) = f2bf(p3);
            }

#pragma unroll
            for (int h = 0; h < 2; ++h) {
                bf16x8 pa = *reinterpret_cast<const bf16x8*>(
                    myPs + l15 * 128 + ((h * 64 + lhi * 16) ^ ((l15 & 7) << 4)));
#pragma unroll
                for (int fn = 0; fn < 4; ++fn) {
                    int dr = fn * 16 + l15;
                    bf16x8 vf = *reinterpret_cast<const bf16x8*>(
                        VT + dr * 128 + ((h * 64 + lhi * 16) ^ ((dr & 7) << 4)));
                    o[fn] = __builtin_amdgcn_mfma_f32_16x16x32_bf16(pa, vf, o[fn], 0, 0, 0);
                }
            }
        }

        // epilogue: write z into qkv's q slot (stride QKV_LD)
#pragma unroll
        for (int i = 0; i < 4; ++i) {
            float inv = 1.0f / lrow[i];
            size_t zr = (rowb + qb0 + lhi * 4 + i) * QKV_LD + hcol;
#pragma unroll
            for (int fn = 0; fn < 4; ++fn)
                qkv[zr + fn * 16 + l15] = f2bf(o[fn][i] * inv);
        }
    }
}

// ---------------- launch ----------------
// ws layout (ushort units), peak 33.1 MB (< 37.75 MB proven):
//   qkv   [0,         9437184)   4096x2304; q-cols become z in-place;
//                                later x_ln2 [0,3145728) + hidden [3145728,9437184)
//   winT  [9437184,  11796480)
//   woutT [11796480, 14155776)
//   wqkvT [14155776, 15925248)
//   woT   [15925248, 16515072)
//   bias_cat (fp32)  [16515072, 16519680)
extern "C" void kernel_launch(void* const* d_in, const int* in_sizes, int n_in,
                              void* d_out, int out_size, void* d_ws, size_t ws_size,
                              hipStream_t stream) {
    const float* resid_pre = (const float*)d_in[0];
    const float* W_Q  = (const float*)d_in[1];
    const float* b_Q  = (const float*)d_in[2];
    const float* W_K  = (const float*)d_in[3];
    const float* b_K  = (const float*)d_in[4];
    const float* W_V  = (const float*)d_in[5];
    const float* b_V  = (const float*)d_in[6];
    const float* W_O  = (const float*)d_in[7];
    const float* b_O  = (const float*)d_in[8];
    const float* ln1_w = (const float*)d_in[9];
    const float* ln1_b = (const float*)d_in[10];
    const float* ln2_w = (const float*)d_in[11];
    const float* ln2_b = (const float*)d_in[12];
    const float* W_in  = (const float*)d_in[13];
    const float* b_in  = (const float*)d_in[14];
    const float* W_out = (const float*)d_in[15];
    const float* b_out = (const float*)d_in[16];
    float* out = (float*)d_out;

    ushort_t* ws = (ushort_t*)d_ws;
    ushort_t* qkv    = ws;
    ushort_t* winT   = ws + 9437184;
    ushort_t* woutT  = ws + 11796480;
    ushort_t* wqkvT  = ws + 14155776;
    ushort_t* woT    = ws + 15925248;
    float*    bias_cat = (float*)(ws + 16515072);
    ushort_t* x_ln1  = (ushort_t*)d_out;          // d_out as bf16 scratch
    ushort_t* x_ln2  = ws;                        // qkv dead after W_O gemm
    ushort_t* hidden = ws + 3145728;              // 4096x1536 bf16
    float*    resid_mid = out;

    dim3 blk(256);

    // 0. all weight prep in one launch
    prep_kernel<<<1729, blk, 0, stream>>>(W_Q, W_K, W_V, W_O, W_in, W_out,
                                          b_Q, b_K, b_V,
                                          wqkvT, woT, winT, woutT, bias_cat);
    // 1. ln1 -> x_ln1 (bf16, in d_out)
    ln_kernel<<<ROWS, blk, 0, stream>>>(resid_pre, ln1_w, ln1_b, x_ln1);
    // 2. fused QKV projection
    mfma_gemm<0><<<dim3(18, 32), blk, 0, stream>>>(x_ln1, D_MODEL, wqkvT, D_MODEL,
                                                   bias_cat, nullptr, qkv, QKV_LD, D_MODEL);
    // 3. attention (z in-place into qkv q-slot), pair-balanced
    attn_mfma<<<dim3(16, N_HEADS, BATCH), blk, 0, stream>>>(qkv);
    // 4. W_O projection + residual -> resid_mid (fp32, d_out); A = z at stride 2304
    mfma_gemm<1><<<dim3(6, 32), blk, 0, stream>>>(qkv, QKV_LD, woT, D_MODEL,
                                                  b_O, resid_pre, resid_mid, D_MODEL, D_MODEL);
    // 5. ln2 -> x_ln2
    ln_kernel<<<ROWS, blk, 0, stream>>>(resid_mid, ln2_w, ln2_b, x_ln2);
    // 6-7. MLP, hidden-dim halves, full M each pass
    for (int b = 0; b < 2; ++b) {
        // hidden = gelu(x_ln2 @ W_in[:, b*1536:+1536])
        mfma_gemm<2><<<dim3(12, 32), blk, 0, stream>>>(x_ln2, D_MODEL, winT + b * 1536 * 768, D_MODEL,
                                                       b_in + b * 1536, nullptr, hidden, 1536, D_MODEL);
        if (b == 0) {
            // out = resid_mid + b_out + hidden @ W_out[b half]
            mfma_gemm<1><<<dim3(6, 32), blk, 0, stream>>>(hidden, 1536, woutT + b * 1536, D_MLP,
                                                          b_out, out, out, D_MODEL, 1536);
        } else {
            // out += hidden @ W_out[b half]
            mfma_gemm<3><<<dim3(6, 32), blk, 0, stream>>>(hidden, 1536, woutT + b * 1536, D_MLP,
                                                          nullptr, nullptr, out, D_MODEL, 1536);
        }
    }
}

// Round 11
// 340.011 us; speedup vs baseline: 15.0152x; 1.0977x over previous
//
#include <hip/hip_runtime.h>
#include <math.h>

typedef unsigned short ushort_t;
typedef __attribute__((ext_vector_type(8))) short bf16x8;
typedef __attribute__((ext_vector_type(4))) float f32x4;

// ---------------- constants ----------------
#define D_MODEL 768
#define N_HEADS 12
#define D_HEAD  64
#define D_MLP   3072
#define BATCH   2
#define SEQ     2048
#define ROWS    (BATCH * SEQ)          // 4096
#define LN_EPS  1e-5f
#define QKV_LD  2304                   // combined q|k|v row stride

// ---------------- bf16 helpers ----------------
__device__ __forceinline__ ushort_t f2bf(float f) {
    unsigned u = __float_as_uint(f);
    u += 0x7fffu + ((u >> 16) & 1u);   // round-to-nearest-even
    return (ushort_t)(u >> 16);
}
__device__ __forceinline__ float bf2f(ushort_t u) {
    return __uint_as_float((unsigned)u << 16);
}

#define GLD16(g, l) __builtin_amdgcn_global_load_lds( \
    (const __attribute__((address_space(1))) void*)(g), \
    (__attribute__((address_space(3))) void*)(l), 16, 0, 0)

// ---------------- LayerNorm (fp32 in -> bf16 out) ----------------
__global__ __launch_bounds__(256) void ln_kernel(const float* __restrict__ x,
                                                 const float* __restrict__ w,
                                                 const float* __restrict__ b,
                                                 ushort_t* __restrict__ y) {
    int row = blockIdx.x;
    const float* xr = x + (size_t)row * D_MODEL;
    float v[3];
    float s = 0.f, sq = 0.f;
#pragma unroll
    for (int u = 0; u < 3; ++u) {
        v[u] = xr[threadIdx.x + u * 256];
        s += v[u];
        sq += v[u] * v[u];
    }
#pragma unroll
    for (int off = 32; off >= 1; off >>= 1) {
        s  += __shfl_xor(s, off);
        sq += __shfl_xor(sq, off);
    }
    __shared__ float ss[4], ssq[4];
    int wave = threadIdx.x >> 6;
    int lane = threadIdx.x & 63;
    if (lane == 0) { ss[wave] = s; ssq[wave] = sq; }
    __syncthreads();
    s = ss[0] + ss[1] + ss[2] + ss[3];
    sq = ssq[0] + ssq[1] + ssq[2] + ssq[3];
    float mean = s * (1.0f / D_MODEL);
    float var = sq * (1.0f / D_MODEL) - mean * mean;
    float rstd = rsqrtf(var + LN_EPS);
    ushort_t* yr = y + (size_t)row * D_MODEL;
#pragma unroll
    for (int u = 0; u < 3; ++u) {
        int idx = threadIdx.x + u * 256;
        yr[idx] = f2bf((v[u] - mean) * rstd * w[idx] + b[idx]);
    }
}

// ---------------- GELU (GPT-2 'new', exp form) ----------------
__device__ __forceinline__ float gelu_new_f(float x) {
    float y2 = -1.5957691216057308f * (x + 0.044715f * x * x * x);
    return x / (1.0f + __expf(y2));
}

// ---------------- transpose tile (device fn) ----------------
__device__ __forceinline__ void do_transpose(const float* __restrict__ in, int in_ld, long in_zs,
                                             ushort_t* __restrict__ out, int out_ld, long out_zs,
                                             int bx, int by, int bz) {
    __shared__ float T[64][65];
    long ib = (long)bz * in_zs;
    long ob = (long)bz * out_zs;
    int r0 = bx * 64;
    int c0 = by * 64;
    int tr = threadIdx.x >> 4;
    int tc4 = (threadIdx.x & 15) * 4;
#pragma unroll
    for (int i = 0; i < 4; ++i) {
        int r = i * 16 + tr;
        float4 v = *reinterpret_cast<const float4*>(in + ib + (long)(r0 + r) * in_ld + c0 + tc4);
        T[r][tc4 + 0] = v.x; T[r][tc4 + 1] = v.y;
        T[r][tc4 + 2] = v.z; T[r][tc4 + 3] = v.w;
    }
    __syncthreads();
#pragma unroll
    for (int i = 0; i < 4; ++i) {
        int oc = i * 16 + tr;
        ushort4 o;
        o.x = f2bf(T[tc4 + 0][oc]);
        o.y = f2bf(T[tc4 + 1][oc]);
        o.z = f2bf(T[tc4 + 2][oc]);
        o.w = f2bf(T[tc4 + 3][oc]);
        *reinterpret_cast<ushort4*>(out + ob + (long)(c0 + oc) * out_ld + r0 + tc4) = o;
    }
}

// ---------------- fused weight prep: 6 transposes + bias concat ----------------
__global__ __launch_bounds__(256) void prep_kernel(
        const float* __restrict__ WQ, const float* __restrict__ WK,
        const float* __restrict__ WV, const float* __restrict__ WO,
        const float* __restrict__ Win, const float* __restrict__ Wout,
        const float* __restrict__ bQ, const float* __restrict__ bK,
        const float* __restrict__ bV,
        ushort_t* __restrict__ wqkvT, ushort_t* __restrict__ woT,
        ushort_t* __restrict__ winT, ushort_t* __restrict__ woutT,
        float* __restrict__ bias_cat) {
    int id = blockIdx.x;
    if (id < 432) {                       // W_Q/W_K/W_V: [12 heads][768][64] -> [2304][768]
        int j = id / 144, r = id % 144;
        const float* src = (j == 0) ? WQ : (j == 1) ? WK : WV;
        do_transpose(src, 64, 49152, wqkvT + j * 589824, 768, 49152, r % 12, 0, r / 12);
    } else if (id < 576) {                // W_O [768][768] -> [768][768]^T
        int r = id - 432;
        do_transpose(WO, 768, 0, woT, 768, 0, r % 12, r / 12, 0);
    } else if (id < 1152) {               // W_in [768][3072] -> [3072][768]
        int r = id - 576;
        do_transpose(Win, 3072, 0, winT, 768, 0, r % 12, r / 12, 0);
    } else if (id < 1728) {               // W_out [3072][768] -> [768][3072]
        int r = id - 1152;
        do_transpose(Wout, 768, 0, woutT, 3072, 0, r % 48, r / 48, 0);
    } else {                              // bias concat
        for (int i = threadIdx.x; i < 768; i += 256) {
            bias_cat[i] = bQ[i];
            bias_cat[768 + i] = bK[i];
            bias_cat[1536 + i] = bV[i];
        }
    }
}

// ---------------- bf16 MFMA GEMM, tile TM x 128 ----------------
// TM = 128: 4 waves of 64x64 (FM=4).  TM = 64: 4 waves of 32x64 (FM=2).
// MODE 0: C bf16 = acc + bias
// MODE 1: C fp32 = acc + bias + resid   (resid may alias C)
// MODE 2: C bf16 = gelu(acc + bias)
// MODE 3: C fp32 += acc                 (accumulate in place, no bias)
template <int MODE, int TM>
__global__ __launch_bounds__(256) void mfma_gemm(
        const ushort_t* __restrict__ A, int lda,
        const ushort_t* __restrict__ Bt, int ldb,
        const float* __restrict__ bias,
        const float* __restrict__ resid,
        void* __restrict__ C, int cld, int K) {
    constexpr int FM = TM / 32;          // A-frags per wave
    constexpr int AISS = TM / 32;        // A staging issues (TM*128B / 4096B)
    __shared__ char As[TM * 128];
    __shared__ char Bs[16384];
    int tid = threadIdx.x;
    int lane = tid & 63, wv = tid >> 6;
    int wr = wv >> 1, wc = wv & 1;
    int l15 = lane & 15, lhi = lane >> 4;
    int m0 = blockIdx.y * TM, n0 = blockIdx.x * 128;

    f32x4 acc[FM][4];
#pragma unroll
    for (int i = 0; i < FM; ++i)
#pragma unroll
        for (int j = 0; j < 4; ++j) acc[i][j] = (f32x4)(0.f);

    int srow[4], scol[4];
#pragma unroll
    for (int i = 0; i < 4; ++i) {
        int p = (i * 256 + tid) << 4;
        srow[i] = p >> 7;
        scol[i] = ((p & 127) ^ ((srow[i] & 7) << 4)) >> 1;
    }
    int lbase = wv << 10;

    for (int k0 = 0; k0 < K; k0 += 64) {
#pragma unroll
        for (int i = 0; i < AISS; ++i) {
            const ushort_t* ga = A + (size_t)(m0 + srow[i]) * lda + k0 + scol[i];
            GLD16(ga, As + i * 4096 + lbase);
        }
#pragma unroll
        for (int i = 0; i < 4; ++i) {
            const ushort_t* gb = Bt + (size_t)(n0 + srow[i]) * ldb + k0 + scol[i];
            GLD16(gb, Bs + i * 4096 + lbase);
        }
        __syncthreads();

        bf16x8 af[FM][2], bfr[4][2];
#pragma unroll
        for (int f = 0; f < FM; ++f)
#pragma unroll
            for (int h = 0; h < 2; ++h) {
                int ar = wr * (TM / 2) + f * 16 + l15;
                int ac = h * 64 + lhi * 16;
                af[f][h] = *reinterpret_cast<const bf16x8*>(As + ar * 128 + (ac ^ ((ar & 7) << 4)));
            }
#pragma unroll
        for (int f = 0; f < 4; ++f)
#pragma unroll
            for (int h = 0; h < 2; ++h) {
                int br = wc * 64 + f * 16 + l15;
                int ac = h * 64 + lhi * 16;
                bfr[f][h] = *reinterpret_cast<const bf16x8*>(Bs + br * 128 + (ac ^ ((br & 7) << 4)));
            }
#pragma unroll
        for (int fm = 0; fm < FM; ++fm)
#pragma unroll
            for (int fn = 0; fn < 4; ++fn) {
                acc[fm][fn] = __builtin_amdgcn_mfma_f32_16x16x32_bf16(af[fm][0], bfr[fn][0], acc[fm][fn], 0, 0, 0);
                acc[fm][fn] = __builtin_amdgcn_mfma_f32_16x16x32_bf16(af[fm][1], bfr[fn][1], acc[fm][fn], 0, 0, 0);
            }
        __syncthreads();
    }

#pragma unroll
    for (int fm = 0; fm < FM; ++fm)
#pragma unroll
        for (int fn = 0; fn < 4; ++fn)
#pragma unroll
            for (int i = 0; i < 4; ++i) {
                int m = m0 + wr * (TM / 2) + fm * 16 + lhi * 4 + i;
                int n = n0 + wc * 64 + fn * 16 + l15;
                float v = acc[fm][fn][i];
                if (MODE != 3) v += bias[n];
                if (MODE == 0) {
                    ((ushort_t*)C)[(size_t)m * cld + n] = f2bf(v);
                } else if (MODE == 1) {
                    ((float*)C)[(size_t)m * cld + n] = v + resid[(size_t)m * cld + n];
                } else if (MODE == 2) {
                    ((ushort_t*)C)[(size_t)m * cld + n] = f2bf(gelu_new_f(v));
                } else {
                    ((float*)C)[(size_t)m * cld + n] += v;
                }
            }
}

// ---------------- MFMA causal flash attention, 2-wave pair-balanced ----------------
// grid (32, 12, 2), 128 threads (2 waves), 32 q rows per block (16/wave).
// Block p handles q-tile (63-p) then q-tile p (32-row tiles) -> uniform 33
// kv-tile-steps per block; 768 blocks = 3/CU exactly.
// z written IN-PLACE into qkv's q slot.
__global__ __launch_bounds__(128) void attn_mfma(ushort_t* __restrict__ qkv) {
    __shared__ char Ks[8192];
    __shared__ char VT[8192];
    __shared__ char Ps[4096];   // 2 waves x [16][64] bf16 (swizzled)

    int tid = threadIdx.x;
    int lane = tid & 63, wq = tid >> 6;     // wq 0..1
    int l15 = lane & 15, lhi = lane >> 4;
    int head = blockIdx.y, batch = blockIdx.z;
    size_t rowb = (size_t)batch * SEQ;
    int hcol = head * 64;

    int srow[4], scol[4];
#pragma unroll
    for (int i = 0; i < 4; ++i) {
        int p = (i * 128 + tid) << 4;
        srow[i] = p >> 7;
        scol[i] = ((p & 127) ^ ((srow[i] & 7) << 4)) >> 1;
    }
    char* myPs = Ps + wq * 2048;

    for (int hh = 0; hh < 2; ++hh) {
        int qt = hh ? (int)blockIdx.x : (63 - (int)blockIdx.x);   // 32-row q tiles
        int qb0 = qt * 32 + wq * 16;

        bf16x8 qf[2];
        {
            const ushort_t* qp = qkv + (rowb + qb0 + l15) * QKV_LD + hcol;
            qf[0] = *reinterpret_cast<const bf16x8*>(qp + lhi * 8);
            qf[1] = *reinterpret_cast<const bf16x8*>(qp + 32 + lhi * 8);
        }

        float mrow[4], lrow[4];
        f32x4 o[4];
#pragma unroll
        for (int i = 0; i < 4; ++i) { mrow[i] = -1e30f; lrow[i] = 0.f; o[i] = (f32x4)(0.f); }

        int ntiles = qt >> 1;             // last kv-tile index (64-key tiles)
        for (int t = 0; t <= ntiles; ++t) {
            int kt = t << 6;
            __syncthreads();
#pragma unroll
            for (int i = 0; i < 4; ++i) {
                const ushort_t* gk = qkv + (rowb + kt + srow[i]) * QKV_LD + hcol + 768 + scol[i];
                GLD16(gk, Ks + i * 2048 + (wq << 10));
            }
            {
                const ushort_t* vp = qkv + (rowb + kt + lane) * QKV_LD + hcol + 1536 + wq * 32;
#pragma unroll
                for (int u = 0; u < 4; ++u) {
                    uint4 vv = *reinterpret_cast<const uint4*>(vp + u * 8);
                    int d0 = wq * 32 + u * 8;
                    unsigned arr[4] = {vv.x, vv.y, vv.z, vv.w};
#pragma unroll
                    for (int e2 = 0; e2 < 4; ++e2) {
                        int e = e2 * 2;
                        *(ushort_t*)(VT + (d0 + e) * 128 + ((lane << 1) ^ (e << 4))) =
                            (ushort_t)(arr[e2] & 0xffff);
                        *(ushort_t*)(VT + (d0 + e + 1) * 128 + ((lane << 1) ^ ((e + 1) << 4))) =
                            (ushort_t)(arr[e2] >> 16);
                    }
                }
            }
            __syncthreads();

            f32x4 s[4];
#pragma unroll
            for (int f = 0; f < 4; ++f) s[f] = (f32x4)(0.f);
#pragma unroll
            for (int h = 0; h < 2; ++h)
#pragma unroll
                for (int f = 0; f < 4; ++f) {
                    int kr = f * 16 + l15;
                    bf16x8 kf = *reinterpret_cast<const bf16x8*>(
                        Ks + kr * 128 + ((h * 64 + lhi * 16) ^ ((kr & 7) << 4)));
                    s[f] = __builtin_amdgcn_mfma_f32_16x16x32_bf16(qf[h], kf, s[f], 0, 0, 0);
                }

            bool lastT = (t == ntiles);
#pragma unroll
            for (int i = 0; i < 4; ++i) {
                int q = qb0 + lhi * 4 + i;
                float sv[4];
#pragma unroll
                for (int f = 0; f < 4; ++f) {
                    float x = s[f][i] * 0.125f;
                    if (lastT && (kt + f * 16 + l15 > q)) x = -1e30f;
                    sv[f] = x;
                }
                float tm = fmaxf(fmaxf(sv[0], sv[1]), fmaxf(sv[2], sv[3]));
#pragma unroll
                for (int ofs = 1; ofs <= 8; ofs <<= 1) tm = fmaxf(tm, __shfl_xor(tm, ofs));
                float mn = fmaxf(mrow[i], tm);
                float corr = __expf(mrow[i] - mn);
                mrow[i] = mn;
                float p0 = __expf(sv[0] - mn), p1 = __expf(sv[1] - mn);
                float p2 = __expf(sv[2] - mn), p3 = __expf(sv[3] - mn);
                float su = p0 + p1 + p2 + p3;
#pragma unroll
                for (int ofs = 1; ofs <= 8; ofs <<= 1) su += __shfl_xor(su, ofs);
                lrow[i] = lrow[i] * corr + su;
#pragma unroll
                for (int fn = 0; fn < 4; ++fn) o[fn][i] *= corr;
                int prow = lhi * 4 + i;
                char* pr = myPs + prow * 128;
                int sw = (prow & 7) << 4;
                *(ushort_t*)(pr + (((0 * 16 + l15) << 1) ^ sw)) = f2bf(p0);
                *(ushort_t*)(pr + (((1 * 16 + l15) << 1) ^ sw)) = f2bf(p1);
                *(ushort_t*)(pr + (((2 * 16 + l15) << 1) ^ sw)) = f2bf(p2);
                *(ushort_t*)(pr + (((3 * 16 + l15) << 1) ^ sw)) = f2bf(p3);
            }

#pragma unroll
            for (int h = 0; h < 2; ++h) {
                bf16x8 pa = *reinterpret_cast<const bf16x8*>(
                    myPs + l15 * 128 + ((h * 64 + lhi * 16) ^ ((l15 & 7) << 4)));
#pragma unroll
                for (int fn = 0; fn < 4; ++fn) {
                    int dr = fn * 16 + l15;
                    bf16x8 vf = *reinterpret_cast<const bf16x8*>(
                        VT + dr * 128 + ((h * 64 + lhi * 16) ^ ((dr & 7) << 4)));
                    o[fn] = __builtin_amdgcn_mfma_f32_16x16x32_bf16(pa, vf, o[fn], 0, 0, 0);
                }
            }
        }

        // epilogue: write z into qkv's q slot (stride QKV_LD)
#pragma unroll
        for (int i = 0; i < 4; ++i) {
            float inv = 1.0f / lrow[i];
            size_t zr = (rowb + qb0 + lhi * 4 + i) * QKV_LD + hcol;
#pragma unroll
            for (int fn = 0; fn < 4; ++fn)
                qkv[zr + fn * 16 + l15] = f2bf(o[fn][i] * inv);
        }
    }
}

// ---------------- launch ----------------
// ws layout (ushort units), peak 33.1 MB (< 37.75 MB proven):
//   qkv   [0,         9437184)   4096x2304; q-cols become z in-place;
//                                later x_ln2 [0,3145728) + hidden [3145728,9437184)
//   winT  [9437184,  11796480)
//   woutT [11796480, 14155776)
//   wqkvT [14155776, 15925248)
//   woT   [15925248, 16515072)
//   bias_cat (fp32)  [16515072, 16519680)
extern "C" void kernel_launch(void* const* d_in, const int* in_sizes, int n_in,
                              void* d_out, int out_size, void* d_ws, size_t ws_size,
                              hipStream_t stream) {
    const float* resid_pre = (const float*)d_in[0];
    const float* W_Q  = (const float*)d_in[1];
    const float* b_Q  = (const float*)d_in[2];
    const float* W_K  = (const float*)d_in[3];
    const float* b_K  = (const float*)d_in[4];
    const float* W_V  = (const float*)d_in[5];
    const float* b_V  = (const float*)d_in[6];
    const float* W_O  = (const float*)d_in[7];
    const float* b_O  = (const float*)d_in[8];
    const float* ln1_w = (const float*)d_in[9];
    const float* ln1_b = (const float*)d_in[10];
    const float* ln2_w = (const float*)d_in[11];
    const float* ln2_b = (const float*)d_in[12];
    const float* W_in  = (const float*)d_in[13];
    const float* b_in  = (const float*)d_in[14];
    const float* W_out = (const float*)d_in[15];
    const float* b_out = (const float*)d_in[16];
    float* out = (float*)d_out;

    ushort_t* ws = (ushort_t*)d_ws;
    ushort_t* qkv    = ws;
    ushort_t* winT   = ws + 9437184;
    ushort_t* woutT  = ws + 11796480;
    ushort_t* wqkvT  = ws + 14155776;
    ushort_t* woT    = ws + 15925248;
    float*    bias_cat = (float*)(ws + 16515072);
    ushort_t* x_ln1  = (ushort_t*)d_out;          // d_out as bf16 scratch
    ushort_t* x_ln2  = ws;                        // qkv dead after W_O gemm
    ushort_t* hidden = ws + 3145728;              // 4096x1536 bf16
    float*    resid_mid = out;

    dim3 blk(256);

    // 0. all weight prep in one launch
    prep_kernel<<<1729, blk, 0, stream>>>(W_Q, W_K, W_V, W_O, W_in, W_out,
                                          b_Q, b_K, b_V,
                                          wqkvT, woT, winT, woutT, bias_cat);
    // 1. ln1 -> x_ln1 (bf16, in d_out)
    ln_kernel<<<ROWS, blk, 0, stream>>>(resid_pre, ln1_w, ln1_b, x_ln1);
    // 2. fused QKV projection (TM=128, 576 blocks)
    mfma_gemm<0, 128><<<dim3(18, 32), blk, 0, stream>>>(x_ln1, D_MODEL, wqkvT, D_MODEL,
                                                        bias_cat, nullptr, qkv, QKV_LD, D_MODEL);
    // 3. attention (z in-place), 2-wave pair-balanced, 768 blocks
    attn_mfma<<<dim3(32, N_HEADS, BATCH), dim3(128), 0, stream>>>(qkv);
    // 4. W_O projection + residual (TM=64, 384 blocks); A = z at stride 2304
    mfma_gemm<1, 64><<<dim3(6, 64), blk, 0, stream>>>(qkv, QKV_LD, woT, D_MODEL,
                                                      b_O, resid_pre, resid_mid, D_MODEL, D_MODEL);
    // 5. ln2 -> x_ln2
    ln_kernel<<<ROWS, blk, 0, stream>>>(resid_mid, ln2_w, ln2_b, x_ln2);
    // 6-7. MLP, hidden-dim halves, full M, TM=64 grids
    for (int b = 0; b < 2; ++b) {
        // hidden = gelu(x_ln2 @ W_in[:, b*1536:+1536])  (768 blocks)
        mfma_gemm<2, 64><<<dim3(12, 64), blk, 0, stream>>>(x_ln2, D_MODEL, winT + b * 1536 * 768, D_MODEL,
                                                           b_in + b * 1536, nullptr, hidden, 1536, D_MODEL);
        if (b == 0) {
            mfma_gemm<1, 64><<<dim3(6, 64), blk, 0, stream>>>(hidden, 1536, woutT + b * 1536, D_MLP,
                                                              b_out, out, out, D_MODEL, 1536);
        } else {
            mfma_gemm<3, 64><<<dim3(6, 64), blk, 0, stream>>>(hidden, 1536, woutT + b * 1536, D_MLP,
                                                              nullptr, nullptr, out, D_MODEL, 1536);
        }
    }
}